// Round 1
// baseline (1148.877 us; speedup 1.0000x reference)
//
#include <hip/hip_runtime.h>

typedef __attribute__((ext_vector_type(8))) short short8;
typedef __attribute__((ext_vector_type(4))) float floatx4;

#define MFMA_BF16 __builtin_amdgcn_mfma_f32_16x16x32_bf16

__device__ inline unsigned short f2bf(float x){
  unsigned int u = __float_as_uint(x);
  u += 0x7fffu + ((u >> 16) & 1u);
  return (unsigned short)(u >> 16);
}

__device__ inline float wave_sum(float v){
  #pragma unroll
  for(int m=32;m>=1;m>>=1) v += __shfl_xor(v,m);
  return v;
}
__device__ inline float grp16_max(float v){
  v = fmaxf(v, __shfl_xor(v,1)); v = fmaxf(v, __shfl_xor(v,2));
  v = fmaxf(v, __shfl_xor(v,4)); v = fmaxf(v, __shfl_xor(v,8));
  return v;
}
__device__ inline float grp16_sum(float v){
  v += __shfl_xor(v,1); v += __shfl_xor(v,2);
  v += __shfl_xor(v,4); v += __shfl_xor(v,8);
  return v;
}

// ---------------- GroupNorm1 (stats+apply+transpose). x:(BT,C,HW) -> xs:(BT,HW,C)
__global__ __launch_bounds__(256) void gn1_kernel(const float* __restrict__ x,
    const float* __restrict__ w, const float* __restrict__ b, float* __restrict__ xs){
  int g = blockIdx.x, bt = blockIdx.y, tid = threadIdx.x;
  const float* xp = x + ((size_t)bt*512 + g*16)*1024;
  float s=0.f, s2=0.f;
  #pragma unroll
  for(int it=0; it<16; ++it){
    float4 v = *(const float4*)(xp + it*1024 + tid*4);
    s  += v.x+v.y+v.z+v.w;
    s2 += v.x*v.x+v.y*v.y+v.z*v.z+v.w*v.w;
  }
  __shared__ float red[8];
  s = wave_sum(s); s2 = wave_sum(s2);
  int wid = tid>>6;
  if((tid&63)==0){ red[wid*2]=s; red[wid*2+1]=s2; }
  __syncthreads();
  s  = red[0]+red[2]+red[4]+red[6];
  s2 = red[1]+red[3]+red[5]+red[7];
  float mean = s * (1.f/16384.f);
  float var  = s2 * (1.f/16384.f) - mean*mean;
  float rinv = rsqrtf(var + 1e-5f);
  int c = tid & 15, h0 = tid >> 4;
  float sc = w[g*16+c]*rinv;
  float sh = b[g*16+c] - mean*sc;
  const float* xcol = xp + (size_t)c*1024;
  float* op = xs + (size_t)bt*1024*512 + g*16 + c;
  #pragma unroll 4
  for(int it=0; it<64; ++it){
    int hw = h0 + it*16;
    op[(size_t)hw*512] = xcol[hw]*sc + sh;
  }
}

// ---------------- Dual LayerNorm per row: vn (f32+bf16) with lnv params, lnl (bf16)
__global__ __launch_bounds__(256) void ln_dual_kernel(const float* __restrict__ xs,
    const float* __restrict__ lvw, const float* __restrict__ lvb,
    const float* __restrict__ llw, const float* __restrict__ llb,
    float* __restrict__ vn, unsigned short* __restrict__ vnb, unsigned short* __restrict__ lnlb){
  int wid = threadIdx.x>>6, l = threadIdx.x&63;
  size_t row = (size_t)blockIdx.x*4 + wid;
  const float* xp = xs + row*512;
  float4 a = *(const float4*)(xp + l*4);
  float4 c = *(const float4*)(xp + 256 + l*4);
  float s  = a.x+a.y+a.z+a.w + c.x+c.y+c.z+c.w;
  float s2 = a.x*a.x+a.y*a.y+a.z*a.z+a.w*a.w + c.x*c.x+c.y*c.y+c.z*c.z+c.w*c.w;
  s = wave_sum(s); s2 = wave_sum(s2);
  float mean = s*(1.f/512.f);
  float rinv = rsqrtf(s2*(1.f/512.f) - mean*mean + 1e-5f);
  int c0 = l*4, c1 = 256 + l*4;
  float y[8] = {(a.x-mean)*rinv,(a.y-mean)*rinv,(a.z-mean)*rinv,(a.w-mean)*rinv,
                (c.x-mean)*rinv,(c.y-mean)*rinv,(c.z-mean)*rinv,(c.w-mean)*rinv};
  float4 o0, o1;
  o0.x=y[0]*lvw[c0+0]+lvb[c0+0]; o0.y=y[1]*lvw[c0+1]+lvb[c0+1];
  o0.z=y[2]*lvw[c0+2]+lvb[c0+2]; o0.w=y[3]*lvw[c0+3]+lvb[c0+3];
  o1.x=y[4]*lvw[c1+0]+lvb[c1+0]; o1.y=y[5]*lvw[c1+1]+lvb[c1+1];
  o1.z=y[6]*lvw[c1+2]+lvb[c1+2]; o1.w=y[7]*lvw[c1+3]+lvb[c1+3];
  *(float4*)(vn + row*512 + c0) = o0;
  *(float4*)(vn + row*512 + c1) = o1;
  ushort4 h;
  h.x=f2bf(o0.x); h.y=f2bf(o0.y); h.z=f2bf(o0.z); h.w=f2bf(o0.w);
  *(ushort4*)(vnb + row*512 + c0) = h;
  h.x=f2bf(o1.x); h.y=f2bf(o1.y); h.z=f2bf(o1.z); h.w=f2bf(o1.w);
  *(ushort4*)(vnb + row*512 + c1) = h;
  h.x=f2bf(y[0]*llw[c0+0]+llb[c0+0]); h.y=f2bf(y[1]*llw[c0+1]+llb[c0+1]);
  h.z=f2bf(y[2]*llw[c0+2]+llb[c0+2]); h.w=f2bf(y[3]*llw[c0+3]+llb[c0+3]);
  *(ushort4*)(lnlb + row*512 + c0) = h;
  h.x=f2bf(y[4]*llw[c1+0]+llb[c1+0]); h.y=f2bf(y[5]*llw[c1+1]+llb[c1+1]);
  h.z=f2bf(y[6]*llw[c1+2]+llb[c1+2]); h.w=f2bf(y[7]*llw[c1+3]+llb[c1+3]);
  *(ushort4*)(lnlb + row*512 + c1) = h;
}

// ---------------- GN2 stats on token-major xs2:(BT,HW,C)
__global__ __launch_bounds__(256) void gn2_stats_kernel(const float* __restrict__ xs2, float* __restrict__ st){
  int g = blockIdx.x, bt = blockIdx.y, tid = threadIdx.x;
  const float* xp = xs2 + (size_t)bt*1024*512;
  int c4 = (tid&3)*4, h0 = tid>>2;
  float s=0.f, s2=0.f;
  #pragma unroll
  for(int it=0; it<16; ++it){
    int hw = h0 + it*64;
    float4 v = *(const float4*)(xp + (size_t)hw*512 + g*16 + c4);
    s  += v.x+v.y+v.z+v.w;
    s2 += v.x*v.x+v.y*v.y+v.z*v.z+v.w*v.w;
  }
  __shared__ float red[8];
  s = wave_sum(s); s2 = wave_sum(s2);
  int wid = tid>>6;
  if((tid&63)==0){ red[wid*2]=s; red[wid*2+1]=s2; }
  __syncthreads();
  if(tid==0){
    s  = red[0]+red[2]+red[4]+red[6];
    s2 = red[1]+red[3]+red[5]+red[7];
    float mean = s * (1.f/16384.f);
    float var  = s2 * (1.f/16384.f) - mean*mean;
    st[(bt*32+g)*2]   = mean;
    st[(bt*32+g)*2+1] = rsqrtf(var + 1e-5f);
  }
}

// ---------------- fused GN2-apply + LayerNorm (ca_lnv) -> vn2 f32 + bf16
__global__ __launch_bounds__(256) void gn2ln_kernel(const float* __restrict__ xs2, const float* __restrict__ st,
    const float* __restrict__ gw, const float* __restrict__ gb,
    const float* __restrict__ lw, const float* __restrict__ lb,
    float* __restrict__ vn2, unsigned short* __restrict__ vn2b){
  int wid = threadIdx.x>>6, l = threadIdx.x&63;
  size_t row = (size_t)blockIdx.x*4 + wid;
  int bt = (int)(row >> 10);
  const float* xp = xs2 + row*512;
  float4 a = *(const float4*)(xp + l*4);
  float4 c = *(const float4*)(xp + 256 + l*4);
  int c0 = l*4, c1 = 256 + l*4;
  int g0 = c0>>4, g1 = c1>>4;
  float m0 = st[(bt*32+g0)*2], r0 = st[(bt*32+g0)*2+1];
  float m1 = st[(bt*32+g1)*2], r1 = st[(bt*32+g1)*2+1];
  float y[8];
  y[0]=(a.x-m0)*r0*gw[c0+0]+gb[c0+0]; y[1]=(a.y-m0)*r0*gw[c0+1]+gb[c0+1];
  y[2]=(a.z-m0)*r0*gw[c0+2]+gb[c0+2]; y[3]=(a.w-m0)*r0*gw[c0+3]+gb[c0+3];
  y[4]=(c.x-m1)*r1*gw[c1+0]+gb[c1+0]; y[5]=(c.y-m1)*r1*gw[c1+1]+gb[c1+1];
  y[6]=(c.z-m1)*r1*gw[c1+2]+gb[c1+2]; y[7]=(c.w-m1)*r1*gw[c1+3]+gb[c1+3];
  float s=0.f, s2=0.f;
  #pragma unroll
  for(int i=0;i<8;++i){ s += y[i]; s2 += y[i]*y[i]; }
  s = wave_sum(s); s2 = wave_sum(s2);
  float mean = s*(1.f/512.f);
  float rinv = rsqrtf(s2*(1.f/512.f) - mean*mean + 1e-5f);
  float4 o0, o1;
  o0.x=(y[0]-mean)*rinv*lw[c0+0]+lb[c0+0]; o0.y=(y[1]-mean)*rinv*lw[c0+1]+lb[c0+1];
  o0.z=(y[2]-mean)*rinv*lw[c0+2]+lb[c0+2]; o0.w=(y[3]-mean)*rinv*lw[c0+3]+lb[c0+3];
  o1.x=(y[4]-mean)*rinv*lw[c1+0]+lb[c1+0]; o1.y=(y[5]-mean)*rinv*lw[c1+1]+lb[c1+1];
  o1.z=(y[6]-mean)*rinv*lw[c1+2]+lb[c1+2]; o1.w=(y[7]-mean)*rinv*lw[c1+3]+lb[c1+3];
  *(float4*)(vn2 + row*512 + c0) = o0;
  *(float4*)(vn2 + row*512 + c1) = o1;
  ushort4 h;
  h.x=f2bf(o0.x); h.y=f2bf(o0.y); h.z=f2bf(o0.z); h.w=f2bf(o0.w);
  *(ushort4*)(vn2b + row*512 + c0) = h;
  h.x=f2bf(o1.x); h.y=f2bf(o1.y); h.z=f2bf(o1.z); h.w=f2bf(o1.w);
  *(ushort4*)(vn2b + row*512 + c1) = h;
}

// ---------------- context LayerNorm (ca_lnl) -> bf16, 154 rows
__global__ __launch_bounds__(256) void ctxln_kernel(const float* __restrict__ ctx,
    const float* __restrict__ lw, const float* __restrict__ lb, unsigned short* __restrict__ out){
  int wid = threadIdx.x>>6, l = threadIdx.x&63;
  int row = blockIdx.x*4 + wid;
  if(row >= 154) return;
  const float* xp = ctx + (size_t)row*512;
  float4 a = *(const float4*)(xp + l*4);
  float4 c = *(const float4*)(xp + 256 + l*4);
  float s  = a.x+a.y+a.z+a.w + c.x+c.y+c.z+c.w;
  float s2 = a.x*a.x+a.y*a.y+a.z*a.z+a.w*a.w + c.x*c.x+c.y*c.y+c.z*c.z+c.w*c.w;
  s = wave_sum(s); s2 = wave_sum(s2);
  float mean = s*(1.f/512.f);
  float rinv = rsqrtf(s2*(1.f/512.f) - mean*mean + 1e-5f);
  int c0 = l*4, c1 = 256 + l*4;
  ushort4 h;
  h.x=f2bf((a.x-mean)*rinv*lw[c0+0]+lb[c0+0]); h.y=f2bf((a.y-mean)*rinv*lw[c0+1]+lb[c0+1]);
  h.z=f2bf((a.z-mean)*rinv*lw[c0+2]+lb[c0+2]); h.w=f2bf((a.w-mean)*rinv*lw[c0+3]+lb[c0+3]);
  *(ushort4*)(out + (size_t)row*512 + c0) = h;
  h.x=f2bf((c.x-mean)*rinv*lw[c1+0]+lb[c1+0]); h.y=f2bf((c.y-mean)*rinv*lw[c1+1]+lb[c1+1]);
  h.z=f2bf((c.z-mean)*rinv*lw[c1+2]+lb[c1+2]); h.w=f2bf((c.w-mean)*rinv*lw[c1+3]+lb[c1+3]);
  *(ushort4*)(out + (size_t)row*512 + c1) = h;
}

// ---------------- weight fp32 -> bf16 (8 weights of 512x512)
__global__ __launch_bounds__(256) void cvtw_kernel(const float* s0, const float* s1, const float* s2,
    const float* s3, const float* s4, const float* s5, const float* s6, const float* s7,
    unsigned short* __restrict__ dst){
  const float* srcs[8] = {s0,s1,s2,s3,s4,s5,s6,s7};
  int w = blockIdx.y;
  const float* src = srcs[w];
  int i = (blockIdx.x*256 + threadIdx.x)*4;
  float4 v = *(const float4*)(src + i);
  ushort4 h; h.x=f2bf(v.x); h.y=f2bf(v.y); h.z=f2bf(v.z); h.w=f2bf(v.w);
  *(ushort4*)(dst + (size_t)w*262144 + i) = h;
}

// ---------------- bf16 MFMA GEMM: out[M,512] = A[M,512] @ W[512,512]^T (+bias, epilogues)
// MODE 0: outb = bf16((acc+bias)*scale)
// MODE 1: outf = r1 + r2 + gamma*(acc+bias)           (token-major)
// MODE 2: outf[bt,c,hw] = r1 + gamma*(acc+bias)       (transposed store, M=16384)
template<int MODE>
__global__ __launch_bounds__(256) void gemm_bt_kernel(const unsigned short* __restrict__ A,
    const unsigned short* __restrict__ W, const float* __restrict__ bias, int M, float scale,
    unsigned short* __restrict__ outb, float* __restrict__ outf,
    const float* __restrict__ r1, const float* __restrict__ r2, const float* __restrict__ gamma){
  int wid = threadIdx.x>>6, l = threadIdx.x&63, quad = l>>4, ln16 = l&15;
  int m0 = blockIdx.x*64 + wid*16;
  int n0 = blockIdx.y*64;
  int arow = m0 + ln16; if(arow > M-1) arow = M-1;
  const unsigned short* Ap = A + (size_t)arow*512 + quad*8;
  const unsigned short* Wp = W + (size_t)(n0+ln16)*512 + quad*8;
  floatx4 acc[4] = {{0,0,0,0},{0,0,0,0},{0,0,0,0},{0,0,0,0}};
  #pragma unroll 2
  for(int k=0;k<512;k+=32){
    short8 av = *(const short8*)(Ap + k);
    #pragma unroll
    for(int nf=0;nf<4;++nf){
      short8 bv = *(const short8*)(Wp + nf*16*512 + k);
      acc[nf] = MFMA_BF16(av, bv, acc[nf], 0,0,0);
    }
  }
  #pragma unroll
  for(int nf=0;nf<4;++nf){
    int col = n0 + nf*16 + ln16;
    float bv = bias[col];
    if(MODE==0){
      #pragma unroll
      for(int r=0;r<4;++r){
        int m = m0 + quad*4 + r;
        if(m < M) outb[(size_t)m*512 + col] = f2bf((acc[nf][r] + bv)*scale);
      }
    } else if(MODE==1){
      float gv = gamma[col];
      #pragma unroll
      for(int r=0;r<4;++r){
        int m = m0 + quad*4 + r;
        size_t ix = (size_t)m*512 + col;
        outf[ix] = r1[ix] + r2[ix] + gv*(acc[nf][r] + bv);
      }
    } else {
      float gv = gamma[col];
      int bt = m0 >> 10;
      int hw0 = (m0 & 1023) + quad*4;
      float4 ov;
      ov.x = r1[(size_t)(m0+quad*4+0)*512+col] + gv*(acc[nf][0]+bv);
      ov.y = r1[(size_t)(m0+quad*4+1)*512+col] + gv*(acc[nf][1]+bv);
      ov.z = r1[(size_t)(m0+quad*4+2)*512+col] + gv*(acc[nf][2]+bv);
      ov.w = r1[(size_t)(m0+quad*4+3)*512+col] + gv*(acc[nf][3]+bv);
      *(float4*)(outf + (size_t)bt*524288 + (size_t)col*1024 + hw0) = ov;
    }
  }
}

// ---------------- spatial flash attention: per (b,idx,head,qtile64)
__global__ __launch_bounds__(256) void attn_sp_kernel(const unsigned short* __restrict__ Q,
    const unsigned short* __restrict__ K, const unsigned short* __restrict__ V,
    unsigned short* __restrict__ O){
  int qt = blockIdx.x, head = blockIdx.y, bz = blockIdx.z;
  int b = bz >> 3, idx = bz & 7;
  int tid = threadIdx.x, wid = tid>>6, l = tid&63, quad = l>>4, ln16 = l&15;
  __shared__ unsigned short vt[64*40];
  __shared__ unsigned short plds[4][512];
  size_t tokq = (size_t)bz*1024 + qt*64 + wid*16 + ln16;
  const unsigned short* qp = Q + tokq*512 + head*64 + quad*8;
  short8 qa0 = *(const short8*)(qp);
  short8 qa1 = *(const short8*)(qp + 32);
  floatx4 o[4] = {{0,0,0,0},{0,0,0,0},{0,0,0,0},{0,0,0,0}};
  float mrun[4] = {-1e30f,-1e30f,-1e30f,-1e30f};
  float lrun[4] = {0.f,0.f,0.f,0.f};
  int nf = (idx==0)?1:2, f0 = (idx==0)?0:(idx-1);
  int stR = tid>>3, stC = (tid&7)*8;
  unsigned short* pw = plds[wid];
  for(int ch=0, nch=nf*32; ch<nch; ++ch){
    int f = f0 + (ch>>5);
    int kk0 = (ch&31)*32;
    size_t kbase = ((size_t)(b*8+f))*1024 + kk0;
    __syncthreads();
    { // stage V^T tile (32 keys x 64 dims)
      const unsigned short* vp = V + (kbase + stR)*512 + head*64 + stC;
      short8 vv = *(const short8*)vp;
      #pragma unroll
      for(int j=0;j<8;++j) vt[(stC+j)*40 + stR] = (unsigned short)vv[j];
    }
    __syncthreads();
    const unsigned short* kp = K + (kbase + ln16)*512 + head*64 + quad*8;
    floatx4 s0={0,0,0,0}, s1={0,0,0,0};
    {
      short8 kb0 = *(const short8*)(kp);
      short8 kb1 = *(const short8*)(kp + 32);
      short8 kb2 = *(const short8*)(kp + 16*512);
      short8 kb3 = *(const short8*)(kp + 16*512 + 32);
      s0 = MFMA_BF16(qa0, kb0, s0, 0,0,0);
      s0 = MFMA_BF16(qa1, kb1, s0, 0,0,0);
      s1 = MFMA_BF16(qa0, kb2, s1, 0,0,0);
      s1 = MFMA_BF16(qa1, kb3, s1, 0,0,0);
    }
    #pragma unroll
    for(int r=0;r<4;++r){
      float mx = grp16_max(fmaxf(s0[r], s1[r]));
      float mnew = fmaxf(mrun[r], mx);
      float p0 = __expf(s0[r]-mnew), p1 = __expf(s1[r]-mnew);
      float rs = grp16_sum(p0+p1);
      float al = __expf(mrun[r]-mnew);
      mrun[r] = mnew;
      lrun[r] = lrun[r]*al + rs;
      o[0][r]*=al; o[1][r]*=al; o[2][r]*=al; o[3][r]*=al;
      pw[(quad*4+r)*32 + ln16] = f2bf(p0);
      pw[(quad*4+r)*32 + 16 + ln16] = f2bf(p1);
    }
    __syncthreads();
    short8 pa = *(const short8*)(pw + ln16*32 + quad*8);
    #pragma unroll
    for(int dc=0;dc<4;++dc){
      short8 vb = *(const short8*)(vt + (dc*16+ln16)*40 + quad*8);
      o[dc] = MFMA_BF16(pa, vb, o[dc], 0,0,0);
    }
  }
  #pragma unroll
  for(int r=0;r<4;++r){
    float inv = 1.f/lrun[r];
    size_t orow = (size_t)bz*1024 + qt*64 + wid*16 + quad*4 + r;
    #pragma unroll
    for(int dc=0;dc<4;++dc)
      O[orow*512 + head*64 + dc*16 + ln16] = f2bf(o[dc][r]*inv);
  }
}

// ---------------- cross attention vs context: 77 keys (3 chunks of 32, masked)
__global__ __launch_bounds__(256) void attn_ca_kernel(const unsigned short* __restrict__ Q,
    const unsigned short* __restrict__ K2, const unsigned short* __restrict__ V2,
    unsigned short* __restrict__ O){
  int qt = blockIdx.x, head = blockIdx.y, bt = blockIdx.z;
  int cb = bt & 1;
  int tid = threadIdx.x, wid = tid>>6, l = tid&63, quad = l>>4, ln16 = l&15;
  __shared__ unsigned short vt[64*40];
  __shared__ unsigned short plds[4][512];
  size_t tokq = (size_t)bt*1024 + qt*64 + wid*16 + ln16;
  const unsigned short* qp = Q + tokq*512 + head*64 + quad*8;
  short8 qa0 = *(const short8*)(qp);
  short8 qa1 = *(const short8*)(qp + 32);
  floatx4 o[4] = {{0,0,0,0},{0,0,0,0},{0,0,0,0},{0,0,0,0}};
  float mrun[4] = {-1e30f,-1e30f,-1e30f,-1e30f};
  float lrun[4] = {0.f,0.f,0.f,0.f};
  int stR = tid>>3, stC = (tid&7)*8;
  unsigned short* pw = plds[wid];
  for(int ch=0; ch<3; ++ch){
    int kk0 = ch*32;
    size_t kbase = (size_t)cb*77 + kk0;
    __syncthreads();
    {
      const unsigned short* vp = V2 + (kbase + stR)*512 + head*64 + stC;
      short8 vv = *(const short8*)vp;
      #pragma unroll
      for(int j=0;j<8;++j) vt[(stC+j)*40 + stR] = (unsigned short)vv[j];
    }
    __syncthreads();
    const unsigned short* kp = K2 + (kbase + ln16)*512 + head*64 + quad*8;
    floatx4 s0={0,0,0,0}, s1={0,0,0,0};
    {
      short8 kb0 = *(const short8*)(kp);
      short8 kb1 = *(const short8*)(kp + 32);
      short8 kb2 = *(const short8*)(kp + 16*512);
      short8 kb3 = *(const short8*)(kp + 16*512 + 32);
      s0 = MFMA_BF16(qa0, kb0, s0, 0,0,0);
      s0 = MFMA_BF16(qa1, kb1, s0, 0,0,0);
      s1 = MFMA_BF16(qa0, kb2, s1, 0,0,0);
      s1 = MFMA_BF16(qa1, kb3, s1, 0,0,0);
    }
    if(kk0 + ln16 >= 77){ s0[0]=-3e38f; s0[1]=-3e38f; s0[2]=-3e38f; s0[3]=-3e38f; }
    if(kk0 + 16 + ln16 >= 77){ s1[0]=-3e38f; s1[1]=-3e38f; s1[2]=-3e38f; s1[3]=-3e38f; }
    #pragma unroll
    for(int r=0;r<4;++r){
      float mx = grp16_max(fmaxf(s0[r], s1[r]));
      float mnew = fmaxf(mrun[r], mx);
      float p0 = __expf(s0[r]-mnew), p1 = __expf(s1[r]-mnew);
      float rs = grp16_sum(p0+p1);
      float al = __expf(mrun[r]-mnew);
      mrun[r] = mnew;
      lrun[r] = lrun[r]*al + rs;
      o[0][r]*=al; o[1][r]*=al; o[2][r]*=al; o[3][r]*=al;
      pw[(quad*4+r)*32 + ln16] = f2bf(p0);
      pw[(quad*4+r)*32 + 16 + ln16] = f2bf(p1);
    }
    __syncthreads();
    short8 pa = *(const short8*)(pw + ln16*32 + quad*8);
    #pragma unroll
    for(int dc=0;dc<4;++dc){
      short8 vb = *(const short8*)(vt + (dc*16+ln16)*40 + quad*8);
      o[dc] = MFMA_BF16(pa, vb, o[dc], 0,0,0);
    }
  }
  #pragma unroll
  for(int r=0;r<4;++r){
    float inv = 1.f/lrun[r];
    size_t orow = (size_t)bt*1024 + qt*64 + wid*16 + quad*4 + r;
    #pragma unroll
    for(int dc=0;dc<4;++dc)
      O[orow*512 + head*64 + dc*16 + ln16] = f2bf(o[dc][r]*inv);
  }
}

extern "C" void kernel_launch(void* const* d_in, const int* in_sizes, int n_in,
                              void* d_out, int out_size, void* d_ws, size_t ws_size,
                              hipStream_t stream) {
  const float* x        = (const float*)d_in[0];
  const float* ctx      = (const float*)d_in[1];
  const float* gn1w     = (const float*)d_in[2];
  const float* gn1b     = (const float*)d_in[3];
  const float* gn2w     = (const float*)d_in[4];
  const float* gn2b     = (const float*)d_in[5];
  const float* sa_lnv_w = (const float*)d_in[6];
  const float* sa_lnv_b = (const float*)d_in[7];
  const float* sa_lnl_w = (const float*)d_in[8];
  const float* sa_lnl_b = (const float*)d_in[9];
  const float* sa_qw    = (const float*)d_in[10];
  const float* sa_qb    = (const float*)d_in[11];
  const float* sa_kw    = (const float*)d_in[12];
  const float* sa_kb    = (const float*)d_in[13];
  const float* sa_vw    = (const float*)d_in[14];
  const float* sa_vb    = (const float*)d_in[15];
  const float* sa_ow    = (const float*)d_in[16];
  const float* sa_ob    = (const float*)d_in[17];
  const float* sa_gamma = (const float*)d_in[18];
  const float* ca_lnv_w = (const float*)d_in[19];
  const float* ca_lnv_b = (const float*)d_in[20];
  const float* ca_lnl_w = (const float*)d_in[21];
  const float* ca_lnl_b = (const float*)d_in[22];
  const float* ca_qw    = (const float*)d_in[23];
  const float* ca_qb    = (const float*)d_in[24];
  const float* ca_kw    = (const float*)d_in[25];
  const float* ca_kb    = (const float*)d_in[26];
  const float* ca_vw    = (const float*)d_in[27];
  const float* ca_vb    = (const float*)d_in[28];
  const float* ca_ow    = (const float*)d_in[29];
  const float* ca_ob    = (const float*)d_in[30];
  const float* ca_gamma = (const float*)d_in[31];

  const size_t BIGF = (size_t)16384*512*4;   // 33.55 MB
  const size_t BIGH = (size_t)16384*512*2;   // 16.78 MB
  char* w8 = (char*)d_ws;
  float*          xs   = (float*)(w8);
  float*          vn   = (float*)(w8 + BIGF);                  // later reused as vn2
  unsigned short* vnb  = (unsigned short*)(w8 + 2*BIGF);       // later vn2b
  unsigned short* lnlb = (unsigned short*)(w8 + 2*BIGF + 1*BIGH);
  unsigned short* Qb   = (unsigned short*)(w8 + 2*BIGF + 2*BIGH);  // later Q2
  unsigned short* Kb   = (unsigned short*)(w8 + 2*BIGF + 3*BIGH);
  unsigned short* Vb   = (unsigned short*)(w8 + 2*BIGF + 4*BIGH);
  unsigned short* Ob   = (unsigned short*)(w8 + 2*BIGF + 5*BIGH);  // later O2
  char* small = w8 + 2*BIGF + 6*BIGH;
  float*          st   = (float*)(small);                 // 4 KB
  unsigned short* ctxb = (unsigned short*)(small + 4096); // 154*512*2
  unsigned short* K2b  = (unsigned short*)(small + 4096 + 157696);            // 192 rows
  unsigned short* V2b  = (unsigned short*)(small + 4096 + 157696 + 196608);
  unsigned short* Wb   = (unsigned short*)(small + 4096 + 157696 + 2*196608); // 8 x 512x512 bf16
  float* xs2 = (float*)d_out;   // d_out doubles as xs2; fully overwritten by final GEMM

  cvtw_kernel<<<dim3(256,8),256,0,stream>>>(sa_qw, sa_kw, sa_vw, sa_ow, ca_qw, ca_kw, ca_vw, ca_ow, Wb);
  gn1_kernel<<<dim3(32,16),256,0,stream>>>(x, gn1w, gn1b, xs);
  ln_dual_kernel<<<4096,256,0,stream>>>(xs, sa_lnv_w, sa_lnv_b, sa_lnl_w, sa_lnl_b, vn, vnb, lnlb);
  gemm_bt_kernel<0><<<dim3(256,8),256,0,stream>>>(vnb,  Wb+0*262144, sa_qb, 16384, 0.125f, Qb, nullptr, nullptr, nullptr, nullptr);
  gemm_bt_kernel<0><<<dim3(256,8),256,0,stream>>>(lnlb, Wb+1*262144, sa_kb, 16384, 1.0f,   Kb, nullptr, nullptr, nullptr, nullptr);
  gemm_bt_kernel<0><<<dim3(256,8),256,0,stream>>>(lnlb, Wb+2*262144, sa_vb, 16384, 1.0f,   Vb, nullptr, nullptr, nullptr, nullptr);
  attn_sp_kernel<<<dim3(16,8,16),256,0,stream>>>(Qb, Kb, Vb, Ob);
  gemm_bt_kernel<1><<<dim3(256,8),256,0,stream>>>(Ob, Wb+3*262144, sa_ob, 16384, 1.0f, nullptr, xs2, xs, vn, sa_gamma);
  gn2_stats_kernel<<<dim3(32,16),256,0,stream>>>(xs2, st);
  gn2ln_kernel<<<4096,256,0,stream>>>(xs2, st, gn2w, gn2b, ca_lnv_w, ca_lnv_b, vn, vnb);
  ctxln_kernel<<<39,256,0,stream>>>(ctx, ca_lnl_w, ca_lnl_b, ctxb);
  gemm_bt_kernel<0><<<dim3(3,8),256,0,stream>>>(ctxb, Wb+5*262144, ca_kb, 154, 1.0f, K2b, nullptr, nullptr, nullptr, nullptr);
  gemm_bt_kernel<0><<<dim3(3,8),256,0,stream>>>(ctxb, Wb+6*262144, ca_vb, 154, 1.0f, V2b, nullptr, nullptr, nullptr, nullptr);
  gemm_bt_kernel<0><<<dim3(256,8),256,0,stream>>>(vnb, Wb+4*262144, ca_qb, 16384, 0.125f, Qb, nullptr, nullptr, nullptr, nullptr);
  attn_ca_kernel<<<dim3(16,8,16),256,0,stream>>>(Qb, K2b, V2b, Ob);
  gemm_bt_kernel<2><<<dim3(256,8),256,0,stream>>>(Ob, Wb+7*262144, ca_ob, 16384, 1.0f, nullptr, (float*)d_out, vn, nullptr, ca_gamma);
}

// Round 2
// 645.067 us; speedup vs baseline: 1.7810x; 1.7810x over previous
//
#include <hip/hip_runtime.h>

typedef __attribute__((ext_vector_type(8))) short short8;
typedef __attribute__((ext_vector_type(4))) float floatx4;
typedef unsigned short ushort_t;

#define MFMA_BF16 __builtin_amdgcn_mfma_f32_16x16x32_bf16

__device__ inline unsigned short f2bf(float x){
  unsigned int u = __float_as_uint(x);
  u += 0x7fffu + ((u >> 16) & 1u);
  return (unsigned short)(u >> 16);
}

__device__ inline float wave_sum(float v){
  #pragma unroll
  for(int m=32;m>=1;m>>=1) v += __shfl_xor(v,m);
  return v;
}
__device__ inline float grp16_sum(float v){
  v += __shfl_xor(v,1); v += __shfl_xor(v,2);
  v += __shfl_xor(v,4); v += __shfl_xor(v,8);
  return v;
}

// ---------------- GroupNorm1 (stats+apply+transpose). x:(BT,C,HW) -> xs:(BT,HW,C)
__global__ __launch_bounds__(256) void gn1_kernel(const float* __restrict__ x,
    const float* __restrict__ w, const float* __restrict__ b, float* __restrict__ xs){
  int g = blockIdx.x, bt = blockIdx.y, tid = threadIdx.x;
  const float* xp = x + ((size_t)bt*512 + g*16)*1024;
  float s=0.f, s2=0.f;
  #pragma unroll
  for(int it=0; it<16; ++it){
    float4 v = *(const float4*)(xp + it*1024 + tid*4);
    s  += v.x+v.y+v.z+v.w;
    s2 += v.x*v.x+v.y*v.y+v.z*v.z+v.w*v.w;
  }
  __shared__ float red[8];
  s = wave_sum(s); s2 = wave_sum(s2);
  int wid = tid>>6;
  if((tid&63)==0){ red[wid*2]=s; red[wid*2+1]=s2; }
  __syncthreads();
  s  = red[0]+red[2]+red[4]+red[6];
  s2 = red[1]+red[3]+red[5]+red[7];
  float mean = s * (1.f/16384.f);
  float var  = s2 * (1.f/16384.f) - mean*mean;
  float rinv = rsqrtf(var + 1e-5f);
  int c = tid & 15, h0 = tid >> 4;
  float sc = w[g*16+c]*rinv;
  float sh = b[g*16+c] - mean*sc;
  const float* xcol = xp + (size_t)c*1024;
  float* op = xs + (size_t)bt*1024*512 + g*16 + c;
  #pragma unroll 4
  for(int it=0; it<64; ++it){
    int hw = h0 + it*16;
    op[(size_t)hw*512] = xcol[hw]*sc + sh;
  }
}

// ---------------- Dual LayerNorm per row: vn (f32+bf16) with lnv params, lnl (bf16)
__global__ __launch_bounds__(256) void ln_dual_kernel(const float* __restrict__ xs,
    const float* __restrict__ lvw, const float* __restrict__ lvb,
    const float* __restrict__ llw, const float* __restrict__ llb,
    float* __restrict__ vn, unsigned short* __restrict__ vnb, unsigned short* __restrict__ lnlb){
  int wid = threadIdx.x>>6, l = threadIdx.x&63;
  size_t row = (size_t)blockIdx.x*4 + wid;
  const float* xp = xs + row*512;
  float4 a = *(const float4*)(xp + l*4);
  float4 c = *(const float4*)(xp + 256 + l*4);
  float s  = a.x+a.y+a.z+a.w + c.x+c.y+c.z+c.w;
  float s2 = a.x*a.x+a.y*a.y+a.z*a.z+a.w*a.w + c.x*c.x+c.y*c.y+c.z*c.z+c.w*c.w;
  s = wave_sum(s); s2 = wave_sum(s2);
  float mean = s*(1.f/512.f);
  float rinv = rsqrtf(s2*(1.f/512.f) - mean*mean + 1e-5f);
  int c0 = l*4, c1 = 256 + l*4;
  float y[8] = {(a.x-mean)*rinv,(a.y-mean)*rinv,(a.z-mean)*rinv,(a.w-mean)*rinv,
                (c.x-mean)*rinv,(c.y-mean)*rinv,(c.z-mean)*rinv,(c.w-mean)*rinv};
  float4 o0, o1;
  o0.x=y[0]*lvw[c0+0]+lvb[c0+0]; o0.y=y[1]*lvw[c0+1]+lvb[c0+1];
  o0.z=y[2]*lvw[c0+2]+lvb[c0+2]; o0.w=y[3]*lvw[c0+3]+lvb[c0+3];
  o1.x=y[4]*lvw[c1+0]+lvb[c1+0]; o1.y=y[5]*lvw[c1+1]+lvb[c1+1];
  o1.z=y[6]*lvw[c1+2]+lvb[c1+2]; o1.w=y[7]*lvw[c1+3]+lvb[c1+3];
  *(float4*)(vn + row*512 + c0) = o0;
  *(float4*)(vn + row*512 + c1) = o1;
  ushort4 h;
  h.x=f2bf(o0.x); h.y=f2bf(o0.y); h.z=f2bf(o0.z); h.w=f2bf(o0.w);
  *(ushort4*)(vnb + row*512 + c0) = h;
  h.x=f2bf(o1.x); h.y=f2bf(o1.y); h.z=f2bf(o1.z); h.w=f2bf(o1.w);
  *(ushort4*)(vnb + row*512 + c1) = h;
  h.x=f2bf(y[0]*llw[c0+0]+llb[c0+0]); h.y=f2bf(y[1]*llw[c0+1]+llb[c0+1]);
  h.z=f2bf(y[2]*llw[c0+2]+llb[c0+2]); h.w=f2bf(y[3]*llw[c0+3]+llb[c0+3]);
  *(ushort4*)(lnlb + row*512 + c0) = h;
  h.x=f2bf(y[4]*llw[c1+0]+llb[c1+0]); h.y=f2bf(y[5]*llw[c1+1]+llb[c1+1]);
  h.z=f2bf(y[6]*llw[c1+2]+llb[c1+2]); h.w=f2bf(y[7]*llw[c1+3]+llb[c1+3]);
  *(ushort4*)(lnlb + row*512 + c1) = h;
}

// ---------------- GN2 stats on token-major xs2:(BT,HW,C)
__global__ __launch_bounds__(256) void gn2_stats_kernel(const float* __restrict__ xs2, float* __restrict__ st){
  int g = blockIdx.x, bt = blockIdx.y, tid = threadIdx.x;
  const float* xp = xs2 + (size_t)bt*1024*512;
  int c4 = (tid&3)*4, h0 = tid>>2;
  float s=0.f, s2=0.f;
  #pragma unroll
  for(int it=0; it<16; ++it){
    int hw = h0 + it*64;
    float4 v = *(const float4*)(xp + (size_t)hw*512 + g*16 + c4);
    s  += v.x+v.y+v.z+v.w;
    s2 += v.x*v.x+v.y*v.y+v.z*v.z+v.w*v.w;
  }
  __shared__ float red[8];
  s = wave_sum(s); s2 = wave_sum(s2);
  int wid = tid>>6;
  if((tid&63)==0){ red[wid*2]=s; red[wid*2+1]=s2; }
  __syncthreads();
  if(tid==0){
    s  = red[0]+red[2]+red[4]+red[6];
    s2 = red[1]+red[3]+red[5]+red[7];
    float mean = s * (1.f/16384.f);
    float var  = s2 * (1.f/16384.f) - mean*mean;
    st[(bt*32+g)*2]   = mean;
    st[(bt*32+g)*2+1] = rsqrtf(var + 1e-5f);
  }
}

// ---------------- fused GN2-apply + LayerNorm (ca_lnv) -> vn2 f32 + bf16
__global__ __launch_bounds__(256) void gn2ln_kernel(const float* __restrict__ xs2, const float* __restrict__ st,
    const float* __restrict__ gw, const float* __restrict__ gb,
    const float* __restrict__ lw, const float* __restrict__ lb,
    float* __restrict__ vn2, unsigned short* __restrict__ vn2b){
  int wid = threadIdx.x>>6, l = threadIdx.x&63;
  size_t row = (size_t)blockIdx.x*4 + wid;
  int bt = (int)(row >> 10);
  const float* xp = xs2 + row*512;
  float4 a = *(const float4*)(xp + l*4);
  float4 c = *(const float4*)(xp + 256 + l*4);
  int c0 = l*4, c1 = 256 + l*4;
  int g0 = c0>>4, g1 = c1>>4;
  float m0 = st[(bt*32+g0)*2], r0 = st[(bt*32+g0)*2+1];
  float m1 = st[(bt*32+g1)*2], r1 = st[(bt*32+g1)*2+1];
  float y[8];
  y[0]=(a.x-m0)*r0*gw[c0+0]+gb[c0+0]; y[1]=(a.y-m0)*r0*gw[c0+1]+gb[c0+1];
  y[2]=(a.z-m0)*r0*gw[c0+2]+gb[c0+2]; y[3]=(a.w-m0)*r0*gw[c0+3]+gb[c0+3];
  y[4]=(c.x-m1)*r1*gw[c1+0]+gb[c1+0]; y[5]=(c.y-m1)*r1*gw[c1+1]+gb[c1+1];
  y[6]=(c.z-m1)*r1*gw[c1+2]+gb[c1+2]; y[7]=(c.w-m1)*r1*gw[c1+3]+gb[c1+3];
  float s=0.f, s2=0.f;
  #pragma unroll
  for(int i=0;i<8;++i){ s += y[i]; s2 += y[i]*y[i]; }
  s = wave_sum(s); s2 = wave_sum(s2);
  float mean = s*(1.f/512.f);
  float rinv = rsqrtf(s2*(1.f/512.f) - mean*mean + 1e-5f);
  float4 o0, o1;
  o0.x=(y[0]-mean)*rinv*lw[c0+0]+lb[c0+0]; o0.y=(y[1]-mean)*rinv*lw[c0+1]+lb[c0+1];
  o0.z=(y[2]-mean)*rinv*lw[c0+2]+lb[c0+2]; o0.w=(y[3]-mean)*rinv*lw[c0+3]+lb[c0+3];
  o1.x=(y[4]-mean)*rinv*lw[c1+0]+lb[c1+0]; o1.y=(y[5]-mean)*rinv*lw[c1+1]+lb[c1+1];
  o1.z=(y[6]-mean)*rinv*lw[c1+2]+lb[c1+2]; o1.w=(y[7]-mean)*rinv*lw[c1+3]+lb[c1+3];
  *(float4*)(vn2 + row*512 + c0) = o0;
  *(float4*)(vn2 + row*512 + c1) = o1;
  ushort4 h;
  h.x=f2bf(o0.x); h.y=f2bf(o0.y); h.z=f2bf(o0.z); h.w=f2bf(o0.w);
  *(ushort4*)(vn2b + row*512 + c0) = h;
  h.x=f2bf(o1.x); h.y=f2bf(o1.y); h.z=f2bf(o1.z); h.w=f2bf(o1.w);
  *(ushort4*)(vn2b + row*512 + c1) = h;
}

// ---------------- context LayerNorm (ca_lnl) -> bf16, 154 rows
__global__ __launch_bounds__(256) void ctxln_kernel(const float* __restrict__ ctx,
    const float* __restrict__ lw, const float* __restrict__ lb, unsigned short* __restrict__ out){
  int wid = threadIdx.x>>6, l = threadIdx.x&63;
  int row = blockIdx.x*4 + wid;
  if(row >= 154) return;
  const float* xp = ctx + (size_t)row*512;
  float4 a = *(const float4*)(xp + l*4);
  float4 c = *(const float4*)(xp + 256 + l*4);
  float s  = a.x+a.y+a.z+a.w + c.x+c.y+c.z+c.w;
  float s2 = a.x*a.x+a.y*a.y+a.z*a.z+a.w*a.w + c.x*c.x+c.y*c.y+c.z*c.z+c.w*c.w;
  s = wave_sum(s); s2 = wave_sum(s2);
  float mean = s*(1.f/512.f);
  float rinv = rsqrtf(s2*(1.f/512.f) - mean*mean + 1e-5f);
  int c0 = l*4, c1 = 256 + l*4;
  ushort4 h;
  h.x=f2bf((a.x-mean)*rinv*lw[c0+0]+lb[c0+0]); h.y=f2bf((a.y-mean)*rinv*lw[c0+1]+lb[c0+1]);
  h.z=f2bf((a.z-mean)*rinv*lw[c0+2]+lb[c0+2]); h.w=f2bf((a.w-mean)*rinv*lw[c0+3]+lb[c0+3]);
  *(ushort4*)(out + (size_t)row*512 + c0) = h;
  h.x=f2bf((c.x-mean)*rinv*lw[c1+0]+lb[c1+0]); h.y=f2bf((c.y-mean)*rinv*lw[c1+1]+lb[c1+1]);
  h.z=f2bf((c.z-mean)*rinv*lw[c1+2]+lb[c1+2]); h.w=f2bf((c.w-mean)*rinv*lw[c1+3]+lb[c1+3]);
  *(ushort4*)(out + (size_t)row*512 + c1) = h;
}

// ---------------- weight fp32 -> bf16 (8 weights of 512x512)
__global__ __launch_bounds__(256) void cvtw_kernel(const float* s0, const float* s1, const float* s2,
    const float* s3, const float* s4, const float* s5, const float* s6, const float* s7,
    unsigned short* __restrict__ dst){
  const float* srcs[8] = {s0,s1,s2,s3,s4,s5,s6,s7};
  int w = blockIdx.y;
  const float* src = srcs[w];
  int i = (blockIdx.x*256 + threadIdx.x)*4;
  float4 v = *(const float4*)(src + i);
  ushort4 h; h.x=f2bf(v.x); h.y=f2bf(v.y); h.z=f2bf(v.z); h.w=f2bf(v.w);
  *(ushort4*)(dst + (size_t)w*262144 + i) = h;
}

// ---------------- bf16 MFMA GEMM v2: wave tile 64m x 64n. out[M,512] = A[M,512] @ W[512,512]^T
// MODE 0: outb = bf16((acc+bias)*scale)                       [natural]
// MODE 1: outf = r1 + r2 + gamma*(acc+bias)                   [natural f32]
// MODE 2: outf[bt,c,hw] = r1 + gamma*(acc+bias)               [transposed f32]
// MODE 3: outb transposed bf16: VT[(m>>10)*512+col][m&1023]
// MODE 4: outb = V2T[(cb*512+col)*128 + key], cb=m>=77,key=m-77cb (M=154)
template<int MODE>
__global__ __launch_bounds__(256) void gemm64_kernel(const unsigned short* __restrict__ A,
    const unsigned short* __restrict__ W, const float* __restrict__ bias, int M, float scale,
    unsigned short* __restrict__ outb, float* __restrict__ outf,
    const float* __restrict__ r1, const float* __restrict__ r2, const float* __restrict__ gamma){
  int wid = threadIdx.x>>6, l = threadIdx.x&63, quad = l>>4, ln16 = l&15;
  int m0 = blockIdx.x*64;
  int n0 = blockIdx.y*256 + wid*64;
  const unsigned short* Ap[4];
  #pragma unroll
  for(int mf=0;mf<4;++mf){
    int arow = m0 + mf*16 + ln16; if(arow > M-1) arow = M-1;
    Ap[mf] = A + (size_t)arow*512 + quad*8;
  }
  const unsigned short* Wp = W + (size_t)(n0+ln16)*512 + quad*8;
  floatx4 acc[4][4];
  #pragma unroll
  for(int mf=0;mf<4;++mf)
    #pragma unroll
    for(int nf=0;nf<4;++nf) acc[mf][nf] = (floatx4){0,0,0,0};
  #pragma unroll 2
  for(int k=0;k<512;k+=32){
    short8 av[4], wv[4];
    #pragma unroll
    for(int mf=0;mf<4;++mf) av[mf] = *(const short8*)(Ap[mf] + k);
    #pragma unroll
    for(int nf=0;nf<4;++nf) wv[nf] = *(const short8*)(Wp + nf*16*512 + k);
    #pragma unroll
    for(int mf=0;mf<4;++mf)
      #pragma unroll
      for(int nf=0;nf<4;++nf)
        acc[mf][nf] = MFMA_BF16(av[mf], wv[nf], acc[mf][nf], 0,0,0);
  }
  #pragma unroll
  for(int mf=0;mf<4;++mf){
    int mb = m0 + mf*16 + quad*4;
    #pragma unroll
    for(int nf=0;nf<4;++nf){
      int col = n0 + nf*16 + ln16;
      float bv = bias[col];
      if(MODE==0){
        #pragma unroll
        for(int r=0;r<4;++r){
          int m = mb + r;
          if(m < M) outb[(size_t)m*512 + col] = f2bf((acc[mf][nf][r] + bv)*scale);
        }
      } else if(MODE==1){
        float gv = gamma[col];
        #pragma unroll
        for(int r=0;r<4;++r){
          size_t ix = (size_t)(mb+r)*512 + col;
          outf[ix] = r1[ix] + r2[ix] + gv*(acc[mf][nf][r] + bv);
        }
      } else if(MODE==2){
        float gv = gamma[col];
        int bt = mb >> 10;
        int hw0 = mb & 1023;
        float4 ov;
        ov.x = r1[(size_t)(mb+0)*512+col] + gv*(acc[mf][nf][0]+bv);
        ov.y = r1[(size_t)(mb+1)*512+col] + gv*(acc[mf][nf][1]+bv);
        ov.z = r1[(size_t)(mb+2)*512+col] + gv*(acc[mf][nf][2]+bv);
        ov.w = r1[(size_t)(mb+3)*512+col] + gv*(acc[mf][nf][3]+bv);
        *(float4*)(outf + (size_t)bt*524288 + (size_t)col*1024 + hw0) = ov;
      } else if(MODE==3){
        int bf = mb >> 10;
        int hw0 = mb & 1023;
        ushort4 h;
        h.x = f2bf(acc[mf][nf][0]+bv); h.y = f2bf(acc[mf][nf][1]+bv);
        h.z = f2bf(acc[mf][nf][2]+bv); h.w = f2bf(acc[mf][nf][3]+bv);
        *(ushort4*)(outb + ((size_t)bf*512 + col)*1024 + hw0) = h;
      } else { // MODE 4
        #pragma unroll
        for(int r=0;r<4;++r){
          int m = mb + r;
          if(m < M){
            int cb = (m >= 77) ? 1 : 0;
            int key = m - 77*cb;
            outb[((size_t)cb*512 + col)*128 + key] = f2bf(acc[mf][nf][r] + bv);
          }
        }
      }
    }
  }
}

// ---------------- spatial flash attention v2: 64-key chunks, 32 q/wave, no running max
// grid (8 qtiles of 128, 8 heads, 16 bz). VT is pre-transposed V: [(b,f)*512+dim][1024 keys]
__global__ __launch_bounds__(256) void attn_sp_kernel(const unsigned short* __restrict__ Q,
    const unsigned short* __restrict__ K, const unsigned short* __restrict__ VT,
    unsigned short* __restrict__ O){
  int qt = blockIdx.x, head = blockIdx.y, bz = blockIdx.z;
  int b = bz >> 3, idx = bz & 7;
  int tid = threadIdx.x, wid = tid>>6, l = tid&63, quad = l>>4, ln16 = l&15;
  __shared__ unsigned short vt[64*72];        // [dim][key] stride 72
  __shared__ unsigned short pl[4*2*64*20];    // per (wave,qtile): [key][row] stride 20
  unsigned short* pw0 = pl + (wid*2+0)*64*20;
  unsigned short* pw1 = pl + (wid*2+1)*64*20;
  size_t qrow = (size_t)bz*1024 + qt*128 + wid*32 + ln16;
  const unsigned short* qp0 = Q + qrow*512 + head*64 + quad*8;
  const unsigned short* qp1 = qp0 + 16*512;
  short8 qa00 = *(const short8*)(qp0), qa01 = *(const short8*)(qp0+32);
  short8 qa10 = *(const short8*)(qp1), qa11 = *(const short8*)(qp1+32);
  floatx4 o[2][4];
  #pragma unroll
  for(int q=0;q<2;++q){ o[q][0]=(floatx4){0,0,0,0}; o[q][1]=(floatx4){0,0,0,0};
                        o[q][2]=(floatx4){0,0,0,0}; o[q][3]=(floatx4){0,0,0,0}; }
  float lr[2][4] = {{0,0,0,0},{0,0,0,0}};
  int nch = idx ? 32 : 16;
  int f0  = idx ? (idx-1) : 0;
  int sd = tid>>2, sk0 = (tid&3)*16;   // staging map: dim sd, keys sk0..sk0+15
  for(int ch=0; ch<nch; ++ch){
    int f = f0 + (ch>>4);
    int kk0 = (ch&15)*64;
    __syncthreads();
    { const unsigned short* vp = VT + (((size_t)(b*8+f)*512) + head*64 + sd)*1024 + kk0 + sk0;
      short8 v0 = *(const short8*)(vp);
      short8 v1 = *(const short8*)(vp + 8);
      *(short8*)(vt + sd*72 + sk0)     = v0;
      *(short8*)(vt + sd*72 + sk0 + 8) = v1; }
    __syncthreads();
    size_t kb = ((size_t)(b*8+f))*1024 + kk0;
    #pragma unroll
    for(int g=0; g<4; ++g){
      const unsigned short* kp = K + (kb + g*16 + ln16)*512 + head*64 + quad*8;
      short8 k0 = *(const short8*)(kp);
      short8 k1 = *(const short8*)(kp + 32);
      floatx4 s0={0,0,0,0}, s1={0,0,0,0};
      s0 = MFMA_BF16(qa00, k0, s0, 0,0,0);
      s0 = MFMA_BF16(qa01, k1, s0, 0,0,0);
      s1 = MFMA_BF16(qa10, k0, s1, 0,0,0);
      s1 = MFMA_BF16(qa11, k1, s1, 0,0,0);
      ushort4 h0, h1;
      { float p0 = __expf(fminf(s0[0],60.f)); lr[0][0]+=p0; h0.x=f2bf(p0);
        float p1 = __expf(fminf(s0[1],60.f)); lr[0][1]+=p1; h0.y=f2bf(p1);
        float p2 = __expf(fminf(s0[2],60.f)); lr[0][2]+=p2; h0.z=f2bf(p2);
        float p3 = __expf(fminf(s0[3],60.f)); lr[0][3]+=p3; h0.w=f2bf(p3);
        float q0 = __expf(fminf(s1[0],60.f)); lr[1][0]+=q0; h1.x=f2bf(q0);
        float q1 = __expf(fminf(s1[1],60.f)); lr[1][1]+=q1; h1.y=f2bf(q1);
        float q2 = __expf(fminf(s1[2],60.f)); lr[1][2]+=q2; h1.z=f2bf(q2);
        float q3 = __expf(fminf(s1[3],60.f)); lr[1][3]+=q3; h1.w=f2bf(q3); }
      *(ushort4*)(pw0 + (g*16+ln16)*20 + quad*4) = h0;
      *(ushort4*)(pw1 + (g*16+ln16)*20 + quad*4) = h1;
    }
    #pragma unroll
    for(int kh=0; kh<2; ++kh){
      short8 pa0, pa1;
      #pragma unroll
      for(int j=0;j<8;++j){
        pa0[j] = (short)pw0[(kh*32 + quad*8 + j)*20 + ln16];
        pa1[j] = (short)pw1[(kh*32 + quad*8 + j)*20 + ln16];
      }
      #pragma unroll
      for(int dc=0; dc<4; ++dc){
        short8 vb = *(const short8*)(vt + (dc*16+ln16)*72 + kh*32 + quad*8);
        o[0][dc] = MFMA_BF16(pa0, vb, o[0][dc], 0,0,0);
        o[1][dc] = MFMA_BF16(pa1, vb, o[1][dc], 0,0,0);
      }
    }
  }
  #pragma unroll
  for(int qq=0; qq<2; ++qq){
    #pragma unroll
    for(int r=0;r<4;++r){
      float lv = grp16_sum(lr[qq][r]);
      float inv = 1.f/lv;
      size_t orow = (size_t)bz*1024 + qt*128 + wid*32 + qq*16 + quad*4 + r;
      #pragma unroll
      for(int dc=0;dc<4;++dc)
        O[orow*512 + head*64 + dc*16 + ln16] = f2bf(o[qq][dc][r]*inv);
    }
  }
}

// ---------------- cross attention v2: 77 keys (2 chunks of 64, masked), 32 q/wave
// K2: [rows cb*77+key][512] (alloc >=208 rows); V2T: [(cb*512+dim)][128 keys] zero-padded
__global__ __launch_bounds__(256) void attn_ca_kernel(const unsigned short* __restrict__ Q,
    const unsigned short* __restrict__ K2, const unsigned short* __restrict__ V2T,
    unsigned short* __restrict__ O){
  int qt = blockIdx.x, head = blockIdx.y, bt = blockIdx.z;
  int cb = bt & 1;
  int tid = threadIdx.x, wid = tid>>6, l = tid&63, quad = l>>4, ln16 = l&15;
  __shared__ unsigned short vt[64*72];
  __shared__ unsigned short pl[4*2*64*20];
  unsigned short* pw0 = pl + (wid*2+0)*64*20;
  unsigned short* pw1 = pl + (wid*2+1)*64*20;
  size_t qrow = (size_t)bt*1024 + qt*128 + wid*32 + ln16;
  const unsigned short* qp0 = Q + qrow*512 + head*64 + quad*8;
  const unsigned short* qp1 = qp0 + 16*512;
  short8 qa00 = *(const short8*)(qp0), qa01 = *(const short8*)(qp0+32);
  short8 qa10 = *(const short8*)(qp1), qa11 = *(const short8*)(qp1+32);
  floatx4 o[2][4];
  #pragma unroll
  for(int q=0;q<2;++q){ o[q][0]=(floatx4){0,0,0,0}; o[q][1]=(floatx4){0,0,0,0};
                        o[q][2]=(floatx4){0,0,0,0}; o[q][3]=(floatx4){0,0,0,0}; }
  float lr[2][4] = {{0,0,0,0},{0,0,0,0}};
  int sd = tid>>2, sk0 = (tid&3)*16;
  for(int ch=0; ch<2; ++ch){
    int kk0 = ch*64;
    __syncthreads();
    { const unsigned short* vp = V2T + (((size_t)cb*512) + head*64 + sd)*128 + kk0 + sk0;
      short8 v0 = *(const short8*)(vp);
      short8 v1 = *(const short8*)(vp + 8);
      *(short8*)(vt + sd*72 + sk0)     = v0;
      *(short8*)(vt + sd*72 + sk0 + 8) = v1; }
    __syncthreads();
    #pragma unroll
    for(int g=0; g<4; ++g){
      int kk = kk0 + g*16 + ln16;
      const unsigned short* kp = K2 + ((size_t)cb*77 + kk)*512 + head*64 + quad*8;
      short8 k0 = *(const short8*)(kp);
      short8 k1 = *(const short8*)(kp + 32);
      floatx4 s0={0,0,0,0}, s1={0,0,0,0};
      s0 = MFMA_BF16(qa00, k0, s0, 0,0,0);
      s0 = MFMA_BF16(qa01, k1, s0, 0,0,0);
      s1 = MFMA_BF16(qa10, k0, s1, 0,0,0);
      s1 = MFMA_BF16(qa11, k1, s1, 0,0,0);
      float msk = (kk < 77) ? 1.f : 0.f;
      ushort4 h0, h1;
      { float p0 = msk*__expf(fminf(s0[0],60.f)); lr[0][0]+=p0; h0.x=f2bf(p0);
        float p1 = msk*__expf(fminf(s0[1],60.f)); lr[0][1]+=p1; h0.y=f2bf(p1);
        float p2 = msk*__expf(fminf(s0[2],60.f)); lr[0][2]+=p2; h0.z=f2bf(p2);
        float p3 = msk*__expf(fminf(s0[3],60.f)); lr[0][3]+=p3; h0.w=f2bf(p3);
        float q0 = msk*__expf(fminf(s1[0],60.f)); lr[1][0]+=q0; h1.x=f2bf(q0);
        float q1 = msk*__expf(fminf(s1[1],60.f)); lr[1][1]+=q1; h1.y=f2bf(q1);
        float q2 = msk*__expf(fminf(s1[2],60.f)); lr[1][2]+=q2; h1.z=f2bf(q2);
        float q3 = msk*__expf(fminf(s1[3],60.f)); lr[1][3]+=q3; h1.w=f2bf(q3); }
      *(ushort4*)(pw0 + (g*16+ln16)*20 + quad*4) = h0;
      *(ushort4*)(pw1 + (g*16+ln16)*20 + quad*4) = h1;
    }
    #pragma unroll
    for(int kh=0; kh<2; ++kh){
      short8 pa0, pa1;
      #pragma unroll
      for(int j=0;j<8;++j){
        pa0[j] = (short)pw0[(kh*32 + quad*8 + j)*20 + ln16];
        pa1[j] = (short)pw1[(kh*32 + quad*8 + j)*20 + ln16];
      }
      #pragma unroll
      for(int dc=0; dc<4; ++dc){
        short8 vb = *(const short8*)(vt + (dc*16+ln16)*72 + kh*32 + quad*8);
        o[0][dc] = MFMA_BF16(pa0, vb, o[0][dc], 0,0,0);
        o[1][dc] = MFMA_BF16(pa1, vb, o[1][dc], 0,0,0);
      }
    }
  }
  #pragma unroll
  for(int qq=0; qq<2; ++qq){
    #pragma unroll
    for(int r=0;r<4;++r){
      float lv = grp16_sum(lr[qq][r]);
      float inv = 1.f/lv;
      size_t orow = (size_t)bt*1024 + qt*128 + wid*32 + qq*16 + quad*4 + r;
      #pragma unroll
      for(int dc=0;dc<4;++dc)
        O[orow*512 + head*64 + dc*16 + ln16] = f2bf(o[qq][dc][r]*inv);
    }
  }
}

extern "C" void kernel_launch(void* const* d_in, const int* in_sizes, int n_in,
                              void* d_out, int out_size, void* d_ws, size_t ws_size,
                              hipStream_t stream) {
  const float* x        = (const float*)d_in[0];
  const float* ctx      = (const float*)d_in[1];
  const float* gn1w     = (const float*)d_in[2];
  const float* gn1b     = (const float*)d_in[3];
  const float* gn2w     = (const float*)d_in[4];
  const float* gn2b     = (const float*)d_in[5];
  const float* sa_lnv_w = (const float*)d_in[6];
  const float* sa_lnv_b = (const float*)d_in[7];
  const float* sa_lnl_w = (const float*)d_in[8];
  const float* sa_lnl_b = (const float*)d_in[9];
  const float* sa_qw    = (const float*)d_in[10];
  const float* sa_qb    = (const float*)d_in[11];
  const float* sa_kw    = (const float*)d_in[12];
  const float* sa_kb    = (const float*)d_in[13];
  const float* sa_vw    = (const float*)d_in[14];
  const float* sa_vb    = (const float*)d_in[15];
  const float* sa_ow    = (const float*)d_in[16];
  const float* sa_ob    = (const float*)d_in[17];
  const float* sa_gamma = (const float*)d_in[18];
  const float* ca_lnv_w = (const float*)d_in[19];
  const float* ca_lnv_b = (const float*)d_in[20];
  const float* ca_lnl_w = (const float*)d_in[21];
  const float* ca_lnl_b = (const float*)d_in[22];
  const float* ca_qw    = (const float*)d_in[23];
  const float* ca_qb    = (const float*)d_in[24];
  const float* ca_kw    = (const float*)d_in[25];
  const float* ca_kb    = (const float*)d_in[26];
  const float* ca_vw    = (const float*)d_in[27];
  const float* ca_vb    = (const float*)d_in[28];
  const float* ca_ow    = (const float*)d_in[29];
  const float* ca_ob    = (const float*)d_in[30];
  const float* ca_gamma = (const float*)d_in[31];

  const size_t BIGF = (size_t)16384*512*4;   // 33.55 MB
  const size_t BIGH = (size_t)16384*512*2;   // 16.78 MB
  char* w8 = (char*)d_ws;
  float*          xs   = (float*)(w8);
  float*          vn   = (float*)(w8 + BIGF);                  // later reused as vn2
  unsigned short* vnb  = (unsigned short*)(w8 + 2*BIGF);       // later vn2b
  unsigned short* lnlb = (unsigned short*)(w8 + 2*BIGF + 1*BIGH);
  unsigned short* Qb   = (unsigned short*)(w8 + 2*BIGF + 2*BIGH);  // later Q2
  unsigned short* Kb   = (unsigned short*)(w8 + 2*BIGF + 3*BIGH);
  unsigned short* VTb  = (unsigned short*)(w8 + 2*BIGF + 4*BIGH);  // V transposed [(bf)*512+c][1024]
  unsigned short* Ob   = (unsigned short*)(w8 + 2*BIGF + 5*BIGH);
  char* small = w8 + 2*BIGF + 6*BIGH;
  float*          st   = (float*)(small);                 // 4 KB
  unsigned short* ctxb = (unsigned short*)(small + 4096); // 154*512*2
  unsigned short* Wb   = (unsigned short*)(small + 4096 + 157696); // 8 x 512x512 bf16
  // K2b / V2T alias the xs buffer (xs is dead after the sa O-projection)
  unsigned short* K2b  = (unsigned short*)(w8);                     // 208 rows x 512 bf16
  unsigned short* V2T  = (unsigned short*)(w8 + 1048576);           // 2*512*128 bf16
  float* xs2 = (float*)d_out;   // d_out doubles as xs2; fully overwritten by final GEMM

  cvtw_kernel<<<dim3(256,8),256,0,stream>>>(sa_qw, sa_kw, sa_vw, sa_ow, ca_qw, ca_kw, ca_vw, ca_ow, Wb);
  gn1_kernel<<<dim3(32,16),256,0,stream>>>(x, gn1w, gn1b, xs);
  ln_dual_kernel<<<4096,256,0,stream>>>(xs, sa_lnv_w, sa_lnv_b, sa_lnl_w, sa_lnl_b, vn, vnb, lnlb);
  gemm64_kernel<0><<<dim3(256,2),256,0,stream>>>(vnb,  Wb+0*262144, sa_qb, 16384, 0.125f, Qb, nullptr, nullptr, nullptr, nullptr);
  gemm64_kernel<0><<<dim3(256,2),256,0,stream>>>(lnlb, Wb+1*262144, sa_kb, 16384, 1.0f,   Kb, nullptr, nullptr, nullptr, nullptr);
  gemm64_kernel<3><<<dim3(256,2),256,0,stream>>>(lnlb, Wb+2*262144, sa_vb, 16384, 1.0f,   VTb, nullptr, nullptr, nullptr, nullptr);
  attn_sp_kernel<<<dim3(8,8,16),256,0,stream>>>(Qb, Kb, VTb, Ob);
  gemm64_kernel<1><<<dim3(256,2),256,0,stream>>>(Ob, Wb+3*262144, sa_ob, 16384, 1.0f, nullptr, xs2, xs, vn, sa_gamma);
  gn2_stats_kernel<<<dim3(32,16),256,0,stream>>>(xs2, st);
  gn2ln_kernel<<<4096,256,0,stream>>>(xs2, st, gn2w, gn2b, ca_lnv_w, ca_lnv_b, vn, vnb);
  ctxln_kernel<<<39,256,0,stream>>>(ctx, ca_lnl_w, ca_lnl_b, ctxb);
  gemm64_kernel<0><<<dim3(3,2),256,0,stream>>>(ctxb, Wb+5*262144, ca_kb, 154, 1.0f, K2b, nullptr, nullptr, nullptr, nullptr);
  hipMemsetAsync(V2T, 0, (size_t)2*512*128*2, stream);
  gemm64_kernel<4><<<dim3(3,2),256,0,stream>>>(ctxb, Wb+6*262144, ca_vb, 154, 1.0f, V2T, nullptr, nullptr, nullptr, nullptr);
  gemm64_kernel<0><<<dim3(256,2),256,0,stream>>>(vnb, Wb+4*262144, ca_qb, 16384, 0.125f, Qb, nullptr, nullptr, nullptr, nullptr);
  attn_ca_kernel<<<dim3(8,8,16),256,0,stream>>>(Qb, K2b, V2T, Ob);
  gemm64_kernel<2><<<dim3(256,2),256,0,stream>>>(Ob, Wb+7*262144, ca_ob, 16384, 1.0f, nullptr, (float*)d_out, vn, nullptr, ca_gamma);
}

// Round 3
// 595.512 us; speedup vs baseline: 1.9292x; 1.0832x over previous
//
#include <hip/hip_runtime.h>

typedef __attribute__((ext_vector_type(8))) short short8;
typedef __attribute__((ext_vector_type(4))) float floatx4;

#define MFMA_BF16 __builtin_amdgcn_mfma_f32_16x16x32_bf16
#define LOG2E 1.44269504088896340736f

__device__ inline unsigned short f2bf(float x){
  unsigned int u = __float_as_uint(x);
  u += 0x7fffu + ((u >> 16) & 1u);
  return (unsigned short)(u >> 16);
}
// truncating bf16 pair pack: (hi<<16)|lo, 1 instr
__device__ inline unsigned pack_bf(float lo, float hi){
  return __builtin_amdgcn_perm(__float_as_uint(hi), __float_as_uint(lo), 0x07060302u);
}

__device__ inline float wave_sum(float v){
  #pragma unroll
  for(int m=32;m>=1;m>>=1) v += __shfl_xor(v,m);
  return v;
}

// ---------------- GroupNorm1 (stats+apply+transpose). x:(BT,C,HW) -> xs:(BT,HW,C)
__global__ __launch_bounds__(256) void gn1_kernel(const float* __restrict__ x,
    const float* __restrict__ w, const float* __restrict__ b, float* __restrict__ xs){
  int g = blockIdx.x, bt = blockIdx.y, tid = threadIdx.x;
  const float* xp = x + ((size_t)bt*512 + g*16)*1024;
  float s=0.f, s2=0.f;
  #pragma unroll
  for(int it=0; it<16; ++it){
    float4 v = *(const float4*)(xp + it*1024 + tid*4);
    s  += v.x+v.y+v.z+v.w;
    s2 += v.x*v.x+v.y*v.y+v.z*v.z+v.w*v.w;
  }
  __shared__ float red[8];
  s = wave_sum(s); s2 = wave_sum(s2);
  int wid = tid>>6;
  if((tid&63)==0){ red[wid*2]=s; red[wid*2+1]=s2; }
  __syncthreads();
  s  = red[0]+red[2]+red[4]+red[6];
  s2 = red[1]+red[3]+red[5]+red[7];
  float mean = s * (1.f/16384.f);
  float var  = s2 * (1.f/16384.f) - mean*mean;
  float rinv = rsqrtf(var + 1e-5f);
  int c = tid & 15, h0 = tid >> 4;
  float sc = w[g*16+c]*rinv;
  float sh = b[g*16+c] - mean*sc;
  const float* xcol = xp + (size_t)c*1024;
  float* op = xs + (size_t)bt*1024*512 + g*16 + c;
  #pragma unroll 4
  for(int it=0; it<64; ++it){
    int hw = h0 + it*16;
    op[(size_t)hw*512] = xcol[hw]*sc + sh;
  }
}

// ---------------- Dual LayerNorm per row: vn (f32+bf16) with lnv params, lnl (bf16)
__global__ __launch_bounds__(256) void ln_dual_kernel(const float* __restrict__ xs,
    const float* __restrict__ lvw, const float* __restrict__ lvb,
    const float* __restrict__ llw, const float* __restrict__ llb,
    float* __restrict__ vn, unsigned short* __restrict__ vnb, unsigned short* __restrict__ lnlb){
  int wid = threadIdx.x>>6, l = threadIdx.x&63;
  size_t row = (size_t)blockIdx.x*4 + wid;
  const float* xp = xs + row*512;
  float4 a = *(const float4*)(xp + l*4);
  float4 c = *(const float4*)(xp + 256 + l*4);
  float s  = a.x+a.y+a.z+a.w + c.x+c.y+c.z+c.w;
  float s2 = a.x*a.x+a.y*a.y+a.z*a.z+a.w*a.w + c.x*c.x+c.y*c.y+c.z*c.z+c.w*c.w;
  s = wave_sum(s); s2 = wave_sum(s2);
  float mean = s*(1.f/512.f);
  float rinv = rsqrtf(s2*(1.f/512.f) - mean*mean + 1e-5f);
  int c0 = l*4, c1 = 256 + l*4;
  float y[8] = {(a.x-mean)*rinv,(a.y-mean)*rinv,(a.z-mean)*rinv,(a.w-mean)*rinv,
                (c.x-mean)*rinv,(c.y-mean)*rinv,(c.z-mean)*rinv,(c.w-mean)*rinv};
  float4 o0, o1;
  o0.x=y[0]*lvw[c0+0]+lvb[c0+0]; o0.y=y[1]*lvw[c0+1]+lvb[c0+1];
  o0.z=y[2]*lvw[c0+2]+lvb[c0+2]; o0.w=y[3]*lvw[c0+3]+lvb[c0+3];
  o1.x=y[4]*lvw[c1+0]+lvb[c1+0]; o1.y=y[5]*lvw[c1+1]+lvb[c1+1];
  o1.z=y[6]*lvw[c1+2]+lvb[c1+2]; o1.w=y[7]*lvw[c1+3]+lvb[c1+3];
  *(float4*)(vn + row*512 + c0) = o0;
  *(float4*)(vn + row*512 + c1) = o1;
  ushort4 h;
  h.x=f2bf(o0.x); h.y=f2bf(o0.y); h.z=f2bf(o0.z); h.w=f2bf(o0.w);
  *(ushort4*)(vnb + row*512 + c0) = h;
  h.x=f2bf(o1.x); h.y=f2bf(o1.y); h.z=f2bf(o1.z); h.w=f2bf(o1.w);
  *(ushort4*)(vnb + row*512 + c1) = h;
  h.x=f2bf(y[0]*llw[c0+0]+llb[c0+0]); h.y=f2bf(y[1]*llw[c0+1]+llb[c0+1]);
  h.z=f2bf(y[2]*llw[c0+2]+llb[c0+2]); h.w=f2bf(y[3]*llw[c0+3]+llb[c0+3]);
  *(ushort4*)(lnlb + row*512 + c0) = h;
  h.x=f2bf(y[4]*llw[c1+0]+llb[c1+0]); h.y=f2bf(y[5]*llw[c1+1]+llb[c1+1]);
  h.z=f2bf(y[6]*llw[c1+2]+llb[c1+2]); h.w=f2bf(y[7]*llw[c1+3]+llb[c1+3]);
  *(ushort4*)(lnlb + row*512 + c1) = h;
}

// ---------------- GN2 stats on token-major xs2:(BT,HW,C)
__global__ __launch_bounds__(256) void gn2_stats_kernel(const float* __restrict__ xs2, float* __restrict__ st){
  int g = blockIdx.x, bt = blockIdx.y, tid = threadIdx.x;
  const float* xp = xs2 + (size_t)bt*1024*512;
  int c4 = (tid&3)*4, h0 = tid>>2;
  float s=0.f, s2=0.f;
  #pragma unroll
  for(int it=0; it<16; ++it){
    int hw = h0 + it*64;
    float4 v = *(const float4*)(xp + (size_t)hw*512 + g*16 + c4);
    s  += v.x+v.y+v.z+v.w;
    s2 += v.x*v.x+v.y*v.y+v.z*v.z+v.w*v.w;
  }
  __shared__ float red[8];
  s = wave_sum(s); s2 = wave_sum(s2);
  int wid = tid>>6;
  if((tid&63)==0){ red[wid*2]=s; red[wid*2+1]=s2; }
  __syncthreads();
  if(tid==0){
    s  = red[0]+red[2]+red[4]+red[6];
    s2 = red[1]+red[3]+red[5]+red[7];
    float mean = s * (1.f/16384.f);
    float var  = s2 * (1.f/16384.f) - mean*mean;
    st[(bt*32+g)*2]   = mean;
    st[(bt*32+g)*2+1] = rsqrtf(var + 1e-5f);
  }
}

// ---------------- fused GN2-apply + LayerNorm (ca_lnv) -> vn2 f32 + bf16
__global__ __launch_bounds__(256) void gn2ln_kernel(const float* __restrict__ xs2, const float* __restrict__ st,
    const float* __restrict__ gw, const float* __restrict__ gb,
    const float* __restrict__ lw, const float* __restrict__ lb,
    float* __restrict__ vn2, unsigned short* __restrict__ vn2b){
  int wid = threadIdx.x>>6, l = threadIdx.x&63;
  size_t row = (size_t)blockIdx.x*4 + wid;
  int bt = (int)(row >> 10);
  const float* xp = xs2 + row*512;
  float4 a = *(const float4*)(xp + l*4);
  float4 c = *(const float4*)(xp + 256 + l*4);
  int c0 = l*4, c1 = 256 + l*4;
  int g0 = c0>>4, g1 = c1>>4;
  float m0 = st[(bt*32+g0)*2], r0 = st[(bt*32+g0)*2+1];
  float m1 = st[(bt*32+g1)*2], r1 = st[(bt*32+g1)*2+1];
  float y[8];
  y[0]=(a.x-m0)*r0*gw[c0+0]+gb[c0+0]; y[1]=(a.y-m0)*r0*gw[c0+1]+gb[c0+1];
  y[2]=(a.z-m0)*r0*gw[c0+2]+gb[c0+2]; y[3]=(a.w-m0)*r0*gw[c0+3]+gb[c0+3];
  y[4]=(c.x-m1)*r1*gw[c1+0]+gb[c1+0]; y[5]=(c.y-m1)*r1*gw[c1+1]+gb[c1+1];
  y[6]=(c.z-m1)*r1*gw[c1+2]+gb[c1+2]; y[7]=(c.w-m1)*r1*gw[c1+3]+gb[c1+3];
  float s=0.f, s2=0.f;
  #pragma unroll
  for(int i=0;i<8;++i){ s += y[i]; s2 += y[i]*y[i]; }
  s = wave_sum(s); s2 = wave_sum(s2);
  float mean = s*(1.f/512.f);
  float rinv = rsqrtf(s2*(1.f/512.f) - mean*mean + 1e-5f);
  float4 o0, o1;
  o0.x=(y[0]-mean)*rinv*lw[c0+0]+lb[c0+0]; o0.y=(y[1]-mean)*rinv*lw[c0+1]+lb[c0+1];
  o0.z=(y[2]-mean)*rinv*lw[c0+2]+lb[c0+2]; o0.w=(y[3]-mean)*rinv*lw[c0+3]+lb[c0+3];
  o1.x=(y[4]-mean)*rinv*lw[c1+0]+lb[c1+0]; o1.y=(y[5]-mean)*rinv*lw[c1+1]+lb[c1+1];
  o1.z=(y[6]-mean)*rinv*lw[c1+2]+lb[c1+2]; o1.w=(y[7]-mean)*rinv*lw[c1+3]+lb[c1+3];
  *(float4*)(vn2 + row*512 + c0) = o0;
  *(float4*)(vn2 + row*512 + c1) = o1;
  ushort4 h;
  h.x=f2bf(o0.x); h.y=f2bf(o0.y); h.z=f2bf(o0.z); h.w=f2bf(o0.w);
  *(ushort4*)(vn2b + row*512 + c0) = h;
  h.x=f2bf(o1.x); h.y=f2bf(o1.y); h.z=f2bf(o1.z); h.w=f2bf(o1.w);
  *(ushort4*)(vn2b + row*512 + c1) = h;
}

// ---------------- context LayerNorm (ca_lnl) -> bf16, 154 rows
__global__ __launch_bounds__(256) void ctxln_kernel(const float* __restrict__ ctx,
    const float* __restrict__ lw, const float* __restrict__ lb, unsigned short* __restrict__ out){
  int wid = threadIdx.x>>6, l = threadIdx.x&63;
  int row = blockIdx.x*4 + wid;
  if(row >= 154) return;
  const float* xp = ctx + (size_t)row*512;
  float4 a = *(const float4*)(xp + l*4);
  float4 c = *(const float4*)(xp + 256 + l*4);
  float s  = a.x+a.y+a.z+a.w + c.x+c.y+c.z+c.w;
  float s2 = a.x*a.x+a.y*a.y+a.z*a.z+a.w*a.w + c.x*c.x+c.y*c.y+c.z*c.z+c.w*c.w;
  s = wave_sum(s); s2 = wave_sum(s2);
  float mean = s*(1.f/512.f);
  float rinv = rsqrtf(s2*(1.f/512.f) - mean*mean + 1e-5f);
  int c0 = l*4, c1 = 256 + l*4;
  ushort4 h;
  h.x=f2bf((a.x-mean)*rinv*lw[c0+0]+lb[c0+0]); h.y=f2bf((a.y-mean)*rinv*lw[c0+1]+lb[c0+1]);
  h.z=f2bf((a.z-mean)*rinv*lw[c0+2]+lb[c0+2]); h.w=f2bf((a.w-mean)*rinv*lw[c0+3]+lb[c0+3]);
  *(ushort4*)(out + (size_t)row*512 + c0) = h;
  h.x=f2bf((c.x-mean)*rinv*lw[c1+0]+lb[c1+0]); h.y=f2bf((c.y-mean)*rinv*lw[c1+1]+lb[c1+1]);
  h.z=f2bf((c.z-mean)*rinv*lw[c1+2]+lb[c1+2]); h.w=f2bf((c.w-mean)*rinv*lw[c1+3]+lb[c1+3]);
  *(ushort4*)(out + (size_t)row*512 + c1) = h;
}

// ---------------- weight fp32 -> bf16 (8 weights of 512x512)
__global__ __launch_bounds__(256) void cvtw_kernel(const float* s0, const float* s1, const float* s2,
    const float* s3, const float* s4, const float* s5, const float* s6, const float* s7,
    unsigned short* __restrict__ dst){
  const float* srcs[8] = {s0,s1,s2,s3,s4,s5,s6,s7};
  int w = blockIdx.y;
  const float* src = srcs[w];
  int i = (blockIdx.x*256 + threadIdx.x)*4;
  float4 v = *(const float4*)(src + i);
  ushort4 h; h.x=f2bf(v.x); h.y=f2bf(v.y); h.z=f2bf(v.z); h.w=f2bf(v.w);
  *(ushort4*)(dst + (size_t)w*262144 + i) = h;
}

// ---------------- bf16 MFMA GEMM: wave tile 64m x 64n. out[M,512] = A[M,512] @ W[512,512]^T
// MODE 0: outb = bf16((acc+bias)*scale)                       [natural]
// MODE 1: outf = r1 + r2 + gamma*(acc+bias)                   [natural f32]
// MODE 2: outf[bt,c,hw] = r1 + gamma*(acc+bias)               [transposed f32]
// MODE 3: outb transposed bf16: VT[(m>>10)*512+col][m&1023]
// MODE 4: outb = V2T[(cb*512+col)*128 + key], cb=m>=77,key=m-77cb (M=154)
template<int MODE>
__global__ __launch_bounds__(256) void gemm64_kernel(const unsigned short* __restrict__ A,
    const unsigned short* __restrict__ W, const float* __restrict__ bias, int M, float scale,
    unsigned short* __restrict__ outb, float* __restrict__ outf,
    const float* __restrict__ r1, const float* __restrict__ r2, const float* __restrict__ gamma){
  int wid = threadIdx.x>>6, l = threadIdx.x&63, quad = l>>4, ln16 = l&15;
  int m0 = blockIdx.x*64;
  int n0 = blockIdx.y*256 + wid*64;
  const unsigned short* Ap[4];
  #pragma unroll
  for(int mf=0;mf<4;++mf){
    int arow = m0 + mf*16 + ln16; if(arow > M-1) arow = M-1;
    Ap[mf] = A + (size_t)arow*512 + quad*8;
  }
  const unsigned short* Wp = W + (size_t)(n0+ln16)*512 + quad*8;
  floatx4 acc[4][4];
  #pragma unroll
  for(int mf=0;mf<4;++mf)
    #pragma unroll
    for(int nf=0;nf<4;++nf) acc[mf][nf] = (floatx4){0,0,0,0};
  #pragma unroll 2
  for(int k=0;k<512;k+=32){
    short8 av[4], wv[4];
    #pragma unroll
    for(int mf=0;mf<4;++mf) av[mf] = *(const short8*)(Ap[mf] + k);
    #pragma unroll
    for(int nf=0;nf<4;++nf) wv[nf] = *(const short8*)(Wp + nf*16*512 + k);
    #pragma unroll
    for(int mf=0;mf<4;++mf)
      #pragma unroll
      for(int nf=0;nf<4;++nf)
        acc[mf][nf] = MFMA_BF16(av[mf], wv[nf], acc[mf][nf], 0,0,0);
  }
  #pragma unroll
  for(int mf=0;mf<4;++mf){
    int mb = m0 + mf*16 + quad*4;
    #pragma unroll
    for(int nf=0;nf<4;++nf){
      int col = n0 + nf*16 + ln16;
      float bv = bias[col];
      if(MODE==0){
        #pragma unroll
        for(int r=0;r<4;++r){
          int m = mb + r;
          if(m < M) outb[(size_t)m*512 + col] = f2bf((acc[mf][nf][r] + bv)*scale);
        }
      } else if(MODE==1){
        float gv = gamma[col];
        #pragma unroll
        for(int r=0;r<4;++r){
          size_t ix = (size_t)(mb+r)*512 + col;
          outf[ix] = r1[ix] + r2[ix] + gv*(acc[mf][nf][r] + bv);
        }
      } else if(MODE==2){
        float gv = gamma[col];
        int bt = mb >> 10;
        int hw0 = mb & 1023;
        float4 ov;
        ov.x = r1[(size_t)(mb+0)*512+col] + gv*(acc[mf][nf][0]+bv);
        ov.y = r1[(size_t)(mb+1)*512+col] + gv*(acc[mf][nf][1]+bv);
        ov.z = r1[(size_t)(mb+2)*512+col] + gv*(acc[mf][nf][2]+bv);
        ov.w = r1[(size_t)(mb+3)*512+col] + gv*(acc[mf][nf][3]+bv);
        *(float4*)(outf + (size_t)bt*524288 + (size_t)col*1024 + hw0) = ov;
      } else if(MODE==3){
        int bf = mb >> 10;
        int hw0 = mb & 1023;
        ushort4 h;
        h.x = f2bf(acc[mf][nf][0]+bv); h.y = f2bf(acc[mf][nf][1]+bv);
        h.z = f2bf(acc[mf][nf][2]+bv); h.w = f2bf(acc[mf][nf][3]+bv);
        *(ushort4*)(outb + ((size_t)bf*512 + col)*1024 + hw0) = h;
      } else { // MODE 4
        #pragma unroll
        for(int r=0;r<4;++r){
          int m = mb + r;
          if(m < M){
            int cb = (m >= 77) ? 1 : 0;
            int key = m - 77*cb;
            outb[((size_t)cb*512 + col)*128 + key] = f2bf(acc[mf][nf][r] + bv);
          }
        }
      }
    }
  }
}

// ---------------- spatial flash attention v3: S^T orientation, no P gather
// Q pre-scaled by 0.125*log2e so p = exp2(s). grid (8 qtiles, 8 heads, 16 bz)
// K staged block-wide in LDS; V^T tile in LDS; P round-trip: b64 write / b128 read, per-wave (no barrier)
__global__ __launch_bounds__(256) void attn_sp_kernel(const unsigned short* __restrict__ Q,
    const unsigned short* __restrict__ K, const unsigned short* __restrict__ VT,
    unsigned short* __restrict__ O){
  int qt = blockIdx.x, head = blockIdx.y, bz = blockIdx.z;
  int b = bz >> 3, idx = bz & 7;
  int tid = threadIdx.x, wid = tid>>6, l = tid&63, quad = l>>4, ln16 = l&15;
  __shared__ unsigned short vt[64*72];       // [dim][key]
  __shared__ unsigned short kt[64*72];       // [key][dim]
  __shared__ unsigned short pl[8*16*72];     // per (wave,grp): P[query][key] stride 72
  unsigned short* pwr = pl + wid*2*1152 + ln16*72 + quad*4;  // write base (+grp*1152, +g*16)
  unsigned short* prd = pl + wid*2*1152 + ln16*72 + quad*8;  // read base  (+grp*1152, +kh*32)
  size_t qrow = (size_t)bz*1024 + qt*128 + wid*32 + ln16;
  const unsigned short* qp0 = Q + qrow*512 + head*64 + quad*8;
  const unsigned short* qp1 = qp0 + 16*512;
  short8 qb00 = *(const short8*)(qp0), qb01 = *(const short8*)(qp0+32);
  short8 qb10 = *(const short8*)(qp1), qb11 = *(const short8*)(qp1+32);
  floatx4 o[2][4];
  #pragma unroll
  for(int q=0;q<2;++q){ o[q][0]=(floatx4){0,0,0,0}; o[q][1]=(floatx4){0,0,0,0};
                        o[q][2]=(floatx4){0,0,0,0}; o[q][3]=(floatx4){0,0,0,0}; }
  float lr[2] = {0.f, 0.f};
  int nch = idx ? 32 : 16;
  int f0  = idx ? (idx-1) : 0;
  int sr = tid>>2, sc0 = (tid&3)*16;
  for(int ch=0; ch<nch; ++ch){
    int f = f0 + (ch>>4);
    int kk0 = (ch&15)*64;
    size_t kb = ((size_t)(b*8+f))*1024 + kk0;
    __syncthreads();
    { const unsigned short* vp = VT + (((size_t)(b*8+f)*512) + head*64 + sr)*1024 + kk0 + sc0;
      *(short8*)(vt + sr*72 + sc0)     = *(const short8*)(vp);
      *(short8*)(vt + sr*72 + sc0 + 8) = *(const short8*)(vp + 8);
      const unsigned short* kp = K + (kb + sr)*512 + head*64 + sc0;
      *(short8*)(kt + sr*72 + sc0)     = *(const short8*)(kp);
      *(short8*)(kt + sr*72 + sc0 + 8) = *(const short8*)(kp + 8); }
    __syncthreads();
    #pragma unroll
    for(int g=0; g<4; ++g){
      const unsigned short* kr = kt + (g*16+ln16)*72 + quad*8;
      short8 k0 = *(const short8*)(kr);
      short8 k1 = *(const short8*)(kr + 32);
      floatx4 s0={0,0,0,0}, s1={0,0,0,0};
      s0 = MFMA_BF16(k0, qb00, s0, 0,0,0);
      s0 = MFMA_BF16(k1, qb01, s0, 0,0,0);
      s1 = MFMA_BF16(k0, qb10, s1, 0,0,0);
      s1 = MFMA_BF16(k1, qb11, s1, 0,0,0);
      float p0 = __builtin_amdgcn_exp2f(s0[0]);
      float p1 = __builtin_amdgcn_exp2f(s0[1]);
      float p2 = __builtin_amdgcn_exp2f(s0[2]);
      float p3 = __builtin_amdgcn_exp2f(s0[3]);
      lr[0] += (p0+p1)+(p2+p3);
      uint2 w0; w0.x = pack_bf(p0,p1); w0.y = pack_bf(p2,p3);
      *(uint2*)(pwr + g*16) = w0;
      float q0 = __builtin_amdgcn_exp2f(s1[0]);
      float q1 = __builtin_amdgcn_exp2f(s1[1]);
      float q2 = __builtin_amdgcn_exp2f(s1[2]);
      float q3 = __builtin_amdgcn_exp2f(s1[3]);
      lr[1] += (q0+q1)+(q2+q3);
      uint2 w1; w1.x = pack_bf(q0,q1); w1.y = pack_bf(q2,q3);
      *(uint2*)(pwr + 1152 + g*16) = w1;
    }
    #pragma unroll
    for(int kh=0; kh<2; ++kh){
      short8 pb0 = *(const short8*)(prd + kh*32);
      short8 pb1 = *(const short8*)(prd + 1152 + kh*32);
      #pragma unroll
      for(int dc=0; dc<4; ++dc){
        short8 vb = *(const short8*)(vt + (dc*16+ln16)*72 + kh*32 + quad*8);
        o[0][dc] = MFMA_BF16(vb, pb0, o[0][dc], 0,0,0);
        o[1][dc] = MFMA_BF16(vb, pb1, o[1][dc], 0,0,0);
      }
    }
  }
  #pragma unroll
  for(int grp=0; grp<2; ++grp){
    float lt = lr[grp];
    lt += __shfl_xor(lt, 16); lt += __shfl_xor(lt, 32);
    float inv = __builtin_amdgcn_rcpf(lt);
    size_t orow = (size_t)bz*1024 + qt*128 + wid*32 + grp*16 + ln16;
    unsigned short* op = O + orow*512 + head*64 + quad*4;
    #pragma unroll
    for(int dc=0; dc<4; ++dc){
      uint2 pk;
      pk.x = pack_bf(o[grp][dc][0]*inv, o[grp][dc][1]*inv);
      pk.y = pack_bf(o[grp][dc][2]*inv, o[grp][dc][3]*inv);
      *(uint2*)(op + dc*16) = pk;
    }
  }
}

// ---------------- cross attention v3: 77 keys (2 chunks of 64, masked), S^T orientation
// K2: rows cb*77+key (buffer has finite data beyond row 154); V2T: [(cb*512+dim)][128] zero-padded
__global__ __launch_bounds__(256) void attn_ca_kernel(const unsigned short* __restrict__ Q,
    const unsigned short* __restrict__ K2, const unsigned short* __restrict__ V2T,
    unsigned short* __restrict__ O){
  int qt = blockIdx.x, head = blockIdx.y, bt = blockIdx.z;
  int cb = bt & 1;
  int tid = threadIdx.x, wid = tid>>6, l = tid&63, quad = l>>4, ln16 = l&15;
  __shared__ unsigned short vt[64*72];
  __shared__ unsigned short kt[64*72];
  __shared__ unsigned short pl[8*16*72];
  unsigned short* pwr = pl + wid*2*1152 + ln16*72 + quad*4;
  unsigned short* prd = pl + wid*2*1152 + ln16*72 + quad*8;
  size_t qrow = (size_t)bt*1024 + qt*128 + wid*32 + ln16;
  const unsigned short* qp0 = Q + qrow*512 + head*64 + quad*8;
  const unsigned short* qp1 = qp0 + 16*512;
  short8 qb00 = *(const short8*)(qp0), qb01 = *(const short8*)(qp0+32);
  short8 qb10 = *(const short8*)(qp1), qb11 = *(const short8*)(qp1+32);
  floatx4 o[2][4];
  #pragma unroll
  for(int q=0;q<2;++q){ o[q][0]=(floatx4){0,0,0,0}; o[q][1]=(floatx4){0,0,0,0};
                        o[q][2]=(floatx4){0,0,0,0}; o[q][3]=(floatx4){0,0,0,0}; }
  float lr[2] = {0.f, 0.f};
  int sr = tid>>2, sc0 = (tid&3)*16;
  for(int ch=0; ch<2; ++ch){
    int kk0 = ch*64;
    __syncthreads();
    { const unsigned short* vp = V2T + (((size_t)cb*512) + head*64 + sr)*128 + kk0 + sc0;
      *(short8*)(vt + sr*72 + sc0)     = *(const short8*)(vp);
      *(short8*)(vt + sr*72 + sc0 + 8) = *(const short8*)(vp + 8);
      const unsigned short* kp = K2 + ((size_t)cb*77 + kk0 + sr)*512 + head*64 + sc0;
      *(short8*)(kt + sr*72 + sc0)     = *(const short8*)(kp);
      *(short8*)(kt + sr*72 + sc0 + 8) = *(const short8*)(kp + 8); }
    __syncthreads();
    #pragma unroll
    for(int g=0; g<4; ++g){
      int kg = kk0 + g*16 + quad*4;   // global key index of reg 0
      const unsigned short* kr = kt + (g*16+ln16)*72 + quad*8;
      short8 k0 = *(const short8*)(kr);
      short8 k1 = *(const short8*)(kr + 32);
      floatx4 s0={0,0,0,0}, s1={0,0,0,0};
      s0 = MFMA_BF16(k0, qb00, s0, 0,0,0);
      s0 = MFMA_BF16(k1, qb01, s0, 0,0,0);
      s1 = MFMA_BF16(k0, qb10, s1, 0,0,0);
      s1 = MFMA_BF16(k1, qb11, s1, 0,0,0);
      float p0 = (kg+0 < 77) ? __builtin_amdgcn_exp2f(s0[0]) : 0.f;
      float p1 = (kg+1 < 77) ? __builtin_amdgcn_exp2f(s0[1]) : 0.f;
      float p2 = (kg+2 < 77) ? __builtin_amdgcn_exp2f(s0[2]) : 0.f;
      float p3 = (kg+3 < 77) ? __builtin_amdgcn_exp2f(s0[3]) : 0.f;
      lr[0] += (p0+p1)+(p2+p3);
      uint2 w0; w0.x = pack_bf(p0,p1); w0.y = pack_bf(p2,p3);
      *(uint2*)(pwr + g*16) = w0;
      float q0 = (kg+0 < 77) ? __builtin_amdgcn_exp2f(s1[0]) : 0.f;
      float q1 = (kg+1 < 77) ? __builtin_amdgcn_exp2f(s1[1]) : 0.f;
      float q2 = (kg+2 < 77) ? __builtin_amdgcn_exp2f(s1[2]) : 0.f;
      float q3 = (kg+3 < 77) ? __builtin_amdgcn_exp2f(s1[3]) : 0.f;
      lr[1] += (q0+q1)+(q2+q3);
      uint2 w1; w1.x = pack_bf(q0,q1); w1.y = pack_bf(q2,q3);
      *(uint2*)(pwr + 1152 + g*16) = w1;
    }
    #pragma unroll
    for(int kh=0; kh<2; ++kh){
      short8 pb0 = *(const short8*)(prd + kh*32);
      short8 pb1 = *(const short8*)(prd + 1152 + kh*32);
      #pragma unroll
      for(int dc=0; dc<4; ++dc){
        short8 vb = *(const short8*)(vt + (dc*16+ln16)*72 + kh*32 + quad*8);
        o[0][dc] = MFMA_BF16(vb, pb0, o[0][dc], 0,0,0);
        o[1][dc] = MFMA_BF16(vb, pb1, o[1][dc], 0,0,0);
      }
    }
  }
  #pragma unroll
  for(int grp=0; grp<2; ++grp){
    float lt = lr[grp];
    lt += __shfl_xor(lt, 16); lt += __shfl_xor(lt, 32);
    float inv = __builtin_amdgcn_rcpf(lt);
    size_t orow = (size_t)bt*1024 + qt*128 + wid*32 + grp*16 + ln16;
    unsigned short* op = O + orow*512 + head*64 + quad*4;
    #pragma unroll
    for(int dc=0; dc<4; ++dc){
      uint2 pk;
      pk.x = pack_bf(o[grp][dc][0]*inv, o[grp][dc][1]*inv);
      pk.y = pack_bf(o[grp][dc][2]*inv, o[grp][dc][3]*inv);
      *(uint2*)(op + dc*16) = pk;
    }
  }
}

extern "C" void kernel_launch(void* const* d_in, const int* in_sizes, int n_in,
                              void* d_out, int out_size, void* d_ws, size_t ws_size,
                              hipStream_t stream) {
  const float* x        = (const float*)d_in[0];
  const float* ctx      = (const float*)d_in[1];
  const float* gn1w     = (const float*)d_in[2];
  const float* gn1b     = (const float*)d_in[3];
  const float* gn2w     = (const float*)d_in[4];
  const float* gn2b     = (const float*)d_in[5];
  const float* sa_lnv_w = (const float*)d_in[6];
  const float* sa_lnv_b = (const float*)d_in[7];
  const float* sa_lnl_w = (const float*)d_in[8];
  const float* sa_lnl_b = (const float*)d_in[9];
  const float* sa_qw    = (const float*)d_in[10];
  const float* sa_qb    = (const float*)d_in[11];
  const float* sa_kw    = (const float*)d_in[12];
  const float* sa_kb    = (const float*)d_in[13];
  const float* sa_vw    = (const float*)d_in[14];
  const float* sa_vb    = (const float*)d_in[15];
  const float* sa_ow    = (const float*)d_in[16];
  const float* sa_ob    = (const float*)d_in[17];
  const float* sa_gamma = (const float*)d_in[18];
  const float* ca_lnv_w = (const float*)d_in[19];
  const float* ca_lnv_b = (const float*)d_in[20];
  const float* ca_lnl_w = (const float*)d_in[21];
  const float* ca_lnl_b = (const float*)d_in[22];
  const float* ca_qw    = (const float*)d_in[23];
  const float* ca_qb    = (const float*)d_in[24];
  const float* ca_kw    = (const float*)d_in[25];
  const float* ca_kb    = (const float*)d_in[26];
  const float* ca_vw    = (const float*)d_in[27];
  const float* ca_vb    = (const float*)d_in[28];
  const float* ca_ow    = (const float*)d_in[29];
  const float* ca_ob    = (const float*)d_in[30];
  const float* ca_gamma = (const float*)d_in[31];

  const size_t BIGF = (size_t)16384*512*4;   // 33.55 MB
  const size_t BIGH = (size_t)16384*512*2;   // 16.78 MB
  char* w8 = (char*)d_ws;
  float*          xs   = (float*)(w8);
  float*          vn   = (float*)(w8 + BIGF);                  // later reused as vn2
  unsigned short* vnb  = (unsigned short*)(w8 + 2*BIGF);       // later vn2b
  unsigned short* lnlb = (unsigned short*)(w8 + 2*BIGF + 1*BIGH);
  unsigned short* Qb   = (unsigned short*)(w8 + 2*BIGF + 2*BIGH);  // later Q2
  unsigned short* Kb   = (unsigned short*)(w8 + 2*BIGF + 3*BIGH);
  unsigned short* VTb  = (unsigned short*)(w8 + 2*BIGF + 4*BIGH);  // V transposed [(bf)*512+c][1024]
  unsigned short* Ob   = (unsigned short*)(w8 + 2*BIGF + 5*BIGH);
  char* small = w8 + 2*BIGF + 6*BIGH;
  float*          st   = (float*)(small);                 // 4 KB
  unsigned short* ctxb = (unsigned short*)(small + 4096); // 154*512*2
  unsigned short* Wb   = (unsigned short*)(small + 4096 + 157696); // 8 x 512x512 bf16
  // K2b / V2T alias the xs buffer (xs is dead after the sa O-projection)
  unsigned short* K2b  = (unsigned short*)(w8);                     // rows 0..153 valid; reads to 204 finite
  unsigned short* V2T  = (unsigned short*)(w8 + 1048576);           // 2*512*128 bf16
  float* xs2 = (float*)d_out;   // d_out doubles as xs2; fully overwritten by final GEMM

  const float QS = 0.125f * LOG2E;   // fold softmax log2e into Q scale (exp2 path)

  cvtw_kernel<<<dim3(256,8),256,0,stream>>>(sa_qw, sa_kw, sa_vw, sa_ow, ca_qw, ca_kw, ca_vw, ca_ow, Wb);
  gn1_kernel<<<dim3(32,16),256,0,stream>>>(x, gn1w, gn1b, xs);
  ln_dual_kernel<<<4096,256,0,stream>>>(xs, sa_lnv_w, sa_lnv_b, sa_lnl_w, sa_lnl_b, vn, vnb, lnlb);
  gemm64_kernel<0><<<dim3(256,2),256,0,stream>>>(vnb,  Wb+0*262144, sa_qb, 16384, QS,   Qb, nullptr, nullptr, nullptr, nullptr);
  gemm64_kernel<0><<<dim3(256,2),256,0,stream>>>(lnlb, Wb+1*262144, sa_kb, 16384, 1.0f, Kb, nullptr, nullptr, nullptr, nullptr);
  gemm64_kernel<3><<<dim3(256,2),256,0,stream>>>(lnlb, Wb+2*262144, sa_vb, 16384, 1.0f, VTb, nullptr, nullptr, nullptr, nullptr);
  attn_sp_kernel<<<dim3(8,8,16),256,0,stream>>>(Qb, Kb, VTb, Ob);
  gemm64_kernel<1><<<dim3(256,2),256,0,stream>>>(Ob, Wb+3*262144, sa_ob, 16384, 1.0f, nullptr, xs2, xs, vn, sa_gamma);
  gn2_stats_kernel<<<dim3(32,16),256,0,stream>>>(xs2, st);
  gn2ln_kernel<<<4096,256,0,stream>>>(xs2, st, gn2w, gn2b, ca_lnv_w, ca_lnv_b, vn, vnb);
  ctxln_kernel<<<39,256,0,stream>>>(ctx, ca_lnl_w, ca_lnl_b, ctxb);
  gemm64_kernel<0><<<dim3(3,2),256,0,stream>>>(ctxb, Wb+5*262144, ca_kb, 154, 1.0f, K2b, nullptr, nullptr, nullptr, nullptr);
  hipMemsetAsync(V2T, 0, (size_t)2*512*128*2, stream);
  gemm64_kernel<4><<<dim3(3,2),256,0,stream>>>(ctxb, Wb+6*262144, ca_vb, 154, 1.0f, V2T, nullptr, nullptr, nullptr, nullptr);
  gemm64_kernel<0><<<dim3(256,2),256,0,stream>>>(vnb, Wb+4*262144, ca_qb, 16384, QS, Qb, nullptr, nullptr, nullptr, nullptr);
  attn_ca_kernel<<<dim3(8,8,16),256,0,stream>>>(Qb, K2b, V2T, Ob);
  gemm64_kernel<2><<<dim3(256,2),256,0,stream>>>(Ob, Wb+7*262144, ca_ob, 16384, 1.0f, nullptr, (float*)d_out, vn, nullptr, ca_gamma);
}

// Round 5
// 585.073 us; speedup vs baseline: 1.9636x; 1.0178x over previous
//
#include <hip/hip_runtime.h>

typedef __attribute__((ext_vector_type(8))) short short8;
typedef __attribute__((ext_vector_type(4))) short short4v;
typedef __attribute__((ext_vector_type(4))) float floatx4;

#define MFMA_BF16 __builtin_amdgcn_mfma_f32_16x16x32_bf16
#define LOG2E 1.44269504088896340736f

// K=16 bf16 MFMA (v_mfma_f32_16x16x16_bf16, A/B = 4 bf16 per lane).
// Guarded so the HIP host pass never parses the target builtin.
__device__ inline floatx4 MFMA16(short4v a, short4v b, floatx4 c){
#if defined(__HIP_DEVICE_COMPILE__)
  return __builtin_amdgcn_mfma_f32_16x16x16bf16_1k(a, b, c, 0, 0, 0);
#else
  return c;
#endif
}

__device__ inline unsigned short f2bf(float x){
  unsigned int u = __float_as_uint(x);
  u += 0x7fffu + ((u >> 16) & 1u);
  return (unsigned short)(u >> 16);
}
// truncating bf16 pair pack: (hi<<16)|lo, 1 instr
__device__ inline unsigned pack_bf(float lo, float hi){
  return __builtin_amdgcn_perm(__float_as_uint(hi), __float_as_uint(lo), 0x07060302u);
}

__device__ inline float wave_sum(float v){
  #pragma unroll
  for(int m=32;m>=1;m>>=1) v += __shfl_xor(v,m);
  return v;
}

// ---------------- GroupNorm1 (stats+apply+transpose). x:(BT,C,HW) -> xs:(BT,HW,C)
__global__ __launch_bounds__(256) void gn1_kernel(const float* __restrict__ x,
    const float* __restrict__ w, const float* __restrict__ b, float* __restrict__ xs){
  int g = blockIdx.x, bt = blockIdx.y, tid = threadIdx.x;
  const float* xp = x + ((size_t)bt*512 + g*16)*1024;
  float s=0.f, s2=0.f;
  #pragma unroll
  for(int it=0; it<16; ++it){
    float4 v = *(const float4*)(xp + it*1024 + tid*4);
    s  += v.x+v.y+v.z+v.w;
    s2 += v.x*v.x+v.y*v.y+v.z*v.z+v.w*v.w;
  }
  __shared__ float red[8];
  s = wave_sum(s); s2 = wave_sum(s2);
  int wid = tid>>6;
  if((tid&63)==0){ red[wid*2]=s; red[wid*2+1]=s2; }
  __syncthreads();
  s  = red[0]+red[2]+red[4]+red[6];
  s2 = red[1]+red[3]+red[5]+red[7];
  float mean = s * (1.f/16384.f);
  float var  = s2 * (1.f/16384.f) - mean*mean;
  float rinv = rsqrtf(var + 1e-5f);
  int c = tid & 15, h0 = tid >> 4;
  float sc = w[g*16+c]*rinv;
  float sh = b[g*16+c] - mean*sc;
  const float* xcol = xp + (size_t)c*1024;
  float* op = xs + (size_t)bt*1024*512 + g*16 + c;
  #pragma unroll 4
  for(int it=0; it<64; ++it){
    int hw = h0 + it*16;
    op[(size_t)hw*512] = xcol[hw]*sc + sh;
  }
}

// ---------------- Dual LayerNorm per row: vn (f32+bf16) with lnv params, lnl (bf16)
__global__ __launch_bounds__(256) void ln_dual_kernel(const float* __restrict__ xs,
    const float* __restrict__ lvw, const float* __restrict__ lvb,
    const float* __restrict__ llw, const float* __restrict__ llb,
    float* __restrict__ vn, unsigned short* __restrict__ vnb, unsigned short* __restrict__ lnlb){
  int wid = threadIdx.x>>6, l = threadIdx.x&63;
  size_t row = (size_t)blockIdx.x*4 + wid;
  const float* xp = xs + row*512;
  float4 a = *(const float4*)(xp + l*4);
  float4 c = *(const float4*)(xp + 256 + l*4);
  float s  = a.x+a.y+a.z+a.w + c.x+c.y+c.z+c.w;
  float s2 = a.x*a.x+a.y*a.y+a.z*a.z+a.w*a.w + c.x*c.x+c.y*c.y+c.z*c.z+c.w*c.w;
  s = wave_sum(s); s2 = wave_sum(s2);
  float mean = s*(1.f/512.f);
  float rinv = rsqrtf(s2*(1.f/512.f) - mean*mean + 1e-5f);
  int c0 = l*4, c1 = 256 + l*4;
  float y[8] = {(a.x-mean)*rinv,(a.y-mean)*rinv,(a.z-mean)*rinv,(a.w-mean)*rinv,
                (c.x-mean)*rinv,(c.y-mean)*rinv,(c.z-mean)*rinv,(c.w-mean)*rinv};
  float4 o0, o1;
  o0.x=y[0]*lvw[c0+0]+lvb[c0+0]; o0.y=y[1]*lvw[c0+1]+lvb[c0+1];
  o0.z=y[2]*lvw[c0+2]+lvb[c0+2]; o0.w=y[3]*lvw[c0+3]+lvb[c0+3];
  o1.x=y[4]*lvw[c1+0]+lvb[c1+0]; o1.y=y[5]*lvw[c1+1]+lvb[c1+1];
  o1.z=y[6]*lvw[c1+2]+lvb[c1+2]; o1.w=y[7]*lvw[c1+3]+lvb[c1+3];
  *(float4*)(vn + row*512 + c0) = o0;
  *(float4*)(vn + row*512 + c1) = o1;
  ushort4 h;
  h.x=f2bf(o0.x); h.y=f2bf(o0.y); h.z=f2bf(o0.z); h.w=f2bf(o0.w);
  *(ushort4*)(vnb + row*512 + c0) = h;
  h.x=f2bf(o1.x); h.y=f2bf(o1.y); h.z=f2bf(o1.z); h.w=f2bf(o1.w);
  *(ushort4*)(vnb + row*512 + c1) = h;
  h.x=f2bf(y[0]*llw[c0+0]+llb[c0+0]); h.y=f2bf(y[1]*llw[c0+1]+llb[c0+1]);
  h.z=f2bf(y[2]*llw[c0+2]+llb[c0+2]); h.w=f2bf(y[3]*llw[c0+3]+llb[c0+3]);
  *(ushort4*)(lnlb + row*512 + c0) = h;
  h.x=f2bf(y[4]*llw[c1+0]+llb[c1+0]); h.y=f2bf(y[5]*llw[c1+1]+llb[c1+1]);
  h.z=f2bf(y[6]*llw[c1+2]+llb[c1+2]); h.w=f2bf(y[7]*llw[c1+3]+llb[c1+3]);
  *(ushort4*)(lnlb + row*512 + c1) = h;
}

// ---------------- GN2 stats on token-major xs2:(BT,HW,C)
__global__ __launch_bounds__(256) void gn2_stats_kernel(const float* __restrict__ xs2, float* __restrict__ st){
  int g = blockIdx.x, bt = blockIdx.y, tid = threadIdx.x;
  const float* xp = xs2 + (size_t)bt*1024*512;
  int c4 = (tid&3)*4, h0 = tid>>2;
  float s=0.f, s2=0.f;
  #pragma unroll
  for(int it=0; it<16; ++it){
    int hw = h0 + it*64;
    float4 v = *(const float4*)(xp + (size_t)hw*512 + g*16 + c4);
    s  += v.x+v.y+v.z+v.w;
    s2 += v.x*v.x+v.y*v.y+v.z*v.z+v.w*v.w;
  }
  __shared__ float red[8];
  s = wave_sum(s); s2 = wave_sum(s2);
  int wid = tid>>6;
  if((tid&63)==0){ red[wid*2]=s; red[wid*2+1]=s2; }
  __syncthreads();
  if(tid==0){
    s  = red[0]+red[2]+red[4]+red[6];
    s2 = red[1]+red[3]+red[5]+red[7];
    float mean = s * (1.f/16384.f);
    float var  = s2 * (1.f/16384.f) - mean*mean;
    st[(bt*32+g)*2]   = mean;
    st[(bt*32+g)*2+1] = rsqrtf(var + 1e-5f);
  }
}

// ---------------- fused GN2-apply + LayerNorm (ca_lnv) -> vn2 f32 + bf16
__global__ __launch_bounds__(256) void gn2ln_kernel(const float* __restrict__ xs2, const float* __restrict__ st,
    const float* __restrict__ gw, const float* __restrict__ gb,
    const float* __restrict__ lw, const float* __restrict__ lb,
    float* __restrict__ vn2, unsigned short* __restrict__ vn2b){
  int wid = threadIdx.x>>6, l = threadIdx.x&63;
  size_t row = (size_t)blockIdx.x*4 + wid;
  int bt = (int)(row >> 10);
  const float* xp = xs2 + row*512;
  float4 a = *(const float4*)(xp + l*4);
  float4 c = *(const float4*)(xp + 256 + l*4);
  int c0 = l*4, c1 = 256 + l*4;
  int g0 = c0>>4, g1 = c1>>4;
  float m0 = st[(bt*32+g0)*2], r0 = st[(bt*32+g0)*2+1];
  float m1 = st[(bt*32+g1)*2], r1 = st[(bt*32+g1)*2+1];
  float y[8];
  y[0]=(a.x-m0)*r0*gw[c0+0]+gb[c0+0]; y[1]=(a.y-m0)*r0*gw[c0+1]+gb[c0+1];
  y[2]=(a.z-m0)*r0*gw[c0+2]+gb[c0+2]; y[3]=(a.w-m0)*r0*gw[c0+3]+gb[c0+3];
  y[4]=(c.x-m1)*r1*gw[c1+0]+gb[c1+0]; y[5]=(c.y-m1)*r1*gw[c1+1]+gb[c1+1];
  y[6]=(c.z-m1)*r1*gw[c1+2]+gb[c1+2]; y[7]=(c.w-m1)*r1*gw[c1+3]+gb[c1+3];
  float s=0.f, s2=0.f;
  #pragma unroll
  for(int i=0;i<8;++i){ s += y[i]; s2 += y[i]*y[i]; }
  s = wave_sum(s); s2 = wave_sum(s2);
  float mean = s*(1.f/512.f);
  float rinv = rsqrtf(s2*(1.f/512.f) - mean*mean + 1e-5f);
  float4 o0, o1;
  o0.x=(y[0]-mean)*rinv*lw[c0+0]+lb[c0+0]; o0.y=(y[1]-mean)*rinv*lw[c0+1]+lb[c0+1];
  o0.z=(y[2]-mean)*rinv*lw[c0+2]+lb[c0+2]; o0.w=(y[3]-mean)*rinv*lw[c0+3]+lb[c0+3];
  o1.x=(y[4]-mean)*rinv*lw[c1+0]+lb[c1+0]; o1.y=(y[5]-mean)*rinv*lw[c1+1]+lb[c1+1];
  o1.z=(y[6]-mean)*rinv*lw[c1+2]+lb[c1+2]; o1.w=(y[7]-mean)*rinv*lw[c1+3]+lb[c1+3];
  *(float4*)(vn2 + row*512 + c0) = o0;
  *(float4*)(vn2 + row*512 + c1) = o1;
  ushort4 h;
  h.x=f2bf(o0.x); h.y=f2bf(o0.y); h.z=f2bf(o0.z); h.w=f2bf(o0.w);
  *(ushort4*)(vn2b + row*512 + c0) = h;
  h.x=f2bf(o1.x); h.y=f2bf(o1.y); h.z=f2bf(o1.z); h.w=f2bf(o1.w);
  *(ushort4*)(vn2b + row*512 + c1) = h;
}

// ---------------- context LayerNorm (ca_lnl) -> bf16, 154 rows
__global__ __launch_bounds__(256) void ctxln_kernel(const float* __restrict__ ctx,
    const float* __restrict__ lw, const float* __restrict__ lb, unsigned short* __restrict__ out){
  int wid = threadIdx.x>>6, l = threadIdx.x&63;
  int row = blockIdx.x*4 + wid;
  if(row >= 154) return;
  const float* xp = ctx + (size_t)row*512;
  float4 a = *(const float4*)(xp + l*4);
  float4 c = *(const float4*)(xp + 256 + l*4);
  float s  = a.x+a.y+a.z+a.w + c.x+c.y+c.z+c.w;
  float s2 = a.x*a.x+a.y*a.y+a.z*a.z+a.w*a.w + c.x*c.x+c.y*c.y+c.z*c.z+c.w*c.w;
  s = wave_sum(s); s2 = wave_sum(s2);
  float mean = s*(1.f/512.f);
  float rinv = rsqrtf(s2*(1.f/512.f) - mean*mean + 1e-5f);
  int c0 = l*4, c1 = 256 + l*4;
  ushort4 h;
  h.x=f2bf((a.x-mean)*rinv*lw[c0+0]+lb[c0+0]); h.y=f2bf((a.y-mean)*rinv*lw[c0+1]+lb[c0+1]);
  h.z=f2bf((a.z-mean)*rinv*lw[c0+2]+lb[c0+2]); h.w=f2bf((a.w-mean)*rinv*lw[c0+3]+lb[c0+3]);
  *(ushort4*)(out + (size_t)row*512 + c0) = h;
  h.x=f2bf((c.x-mean)*rinv*lw[c1+0]+lb[c1+0]); h.y=f2bf((c.y-mean)*rinv*lw[c1+1]+lb[c1+1]);
  h.z=f2bf((c.z-mean)*rinv*lw[c1+2]+lb[c1+2]); h.w=f2bf((c.w-mean)*rinv*lw[c1+3]+lb[c1+3]);
  *(ushort4*)(out + (size_t)row*512 + c1) = h;
}

// ---------------- weight fp32 -> bf16 (8 weights of 512x512)
__global__ __launch_bounds__(256) void cvtw_kernel(const float* s0, const float* s1, const float* s2,
    const float* s3, const float* s4, const float* s5, const float* s6, const float* s7,
    unsigned short* __restrict__ dst){
  const float* srcs[8] = {s0,s1,s2,s3,s4,s5,s6,s7};
  int w = blockIdx.y;
  const float* src = srcs[w];
  int i = (blockIdx.x*256 + threadIdx.x)*4;
  float4 v = *(const float4*)(src + i);
  ushort4 h; h.x=f2bf(v.x); h.y=f2bf(v.y); h.z=f2bf(v.z); h.w=f2bf(v.w);
  *(ushort4*)(dst + (size_t)w*262144 + i) = h;
}

// ---------------- bf16 MFMA GEMM: wave tile 64m x 64n. out[M,512] = A[M,512] @ W[512,512]^T
// MODE 0: outb = bf16((acc+bias)*scale)                       [natural]
// MODE 1: outf = r1 + r2 + gamma*(acc+bias)                   [natural f32]
// MODE 2: outf[bt,c,hw] = r1 + gamma*(acc+bias)               [transposed f32]
// MODE 3: outb transposed bf16: VT[(m>>10)*512+col][m&1023]
// MODE 4: outb = V2T[(cb*512+col)*128 + key], cb=m>=77,key=m-77cb (M=154)
template<int MODE>
__global__ __launch_bounds__(256) void gemm64_kernel(const unsigned short* __restrict__ A,
    const unsigned short* __restrict__ W, const float* __restrict__ bias, int M, float scale,
    unsigned short* __restrict__ outb, float* __restrict__ outf,
    const float* __restrict__ r1, const float* __restrict__ r2, const float* __restrict__ gamma){
  int wid = threadIdx.x>>6, l = threadIdx.x&63, quad = l>>4, ln16 = l&15;
  int m0 = blockIdx.x*64;
  int n0 = blockIdx.y*256 + wid*64;
  const unsigned short* Ap[4];
  #pragma unroll
  for(int mf=0;mf<4;++mf){
    int arow = m0 + mf*16 + ln16; if(arow > M-1) arow = M-1;
    Ap[mf] = A + (size_t)arow*512 + quad*8;
  }
  const unsigned short* Wp = W + (size_t)(n0+ln16)*512 + quad*8;
  floatx4 acc[4][4];
  #pragma unroll
  for(int mf=0;mf<4;++mf)
    #pragma unroll
    for(int nf=0;nf<4;++nf) acc[mf][nf] = (floatx4){0,0,0,0};
  #pragma unroll 2
  for(int k=0;k<512;k+=32){
    short8 av[4], wv[4];
    #pragma unroll
    for(int mf=0;mf<4;++mf) av[mf] = *(const short8*)(Ap[mf] + k);
    #pragma unroll
    for(int nf=0;nf<4;++nf) wv[nf] = *(const short8*)(Wp + nf*16*512 + k);
    #pragma unroll
    for(int mf=0;mf<4;++mf)
      #pragma unroll
      for(int nf=0;nf<4;++nf)
        acc[mf][nf] = MFMA_BF16(av[mf], wv[nf], acc[mf][nf], 0,0,0);
  }
  #pragma unroll
  for(int mf=0;mf<4;++mf){
    int mb = m0 + mf*16 + quad*4;
    #pragma unroll
    for(int nf=0;nf<4;++nf){
      int col = n0 + nf*16 + ln16;
      float bv = bias[col];
      if(MODE==0){
        #pragma unroll
        for(int r=0;r<4;++r){
          int m = mb + r;
          if(m < M) outb[(size_t)m*512 + col] = f2bf((acc[mf][nf][r] + bv)*scale);
        }
      } else if(MODE==1){
        float gv = gamma[col];
        #pragma unroll
        for(int r=0;r<4;++r){
          size_t ix = (size_t)(mb+r)*512 + col;
          outf[ix] = r1[ix] + r2[ix] + gv*(acc[mf][nf][r] + bv);
        }
      } else if(MODE==2){
        float gv = gamma[col];
        int bt = mb >> 10;
        int hw0 = mb & 1023;
        float4 ov;
        ov.x = r1[(size_t)(mb+0)*512+col] + gv*(acc[mf][nf][0]+bv);
        ov.y = r1[(size_t)(mb+1)*512+col] + gv*(acc[mf][nf][1]+bv);
        ov.z = r1[(size_t)(mb+2)*512+col] + gv*(acc[mf][nf][2]+bv);
        ov.w = r1[(size_t)(mb+3)*512+col] + gv*(acc[mf][nf][3]+bv);
        *(float4*)(outf + (size_t)bt*524288 + (size_t)col*1024 + hw0) = ov;
      } else if(MODE==3){
        int bf = mb >> 10;
        int hw0 = mb & 1023;
        ushort4 h;
        h.x = f2bf(acc[mf][nf][0]+bv); h.y = f2bf(acc[mf][nf][1]+bv);
        h.z = f2bf(acc[mf][nf][2]+bv); h.w = f2bf(acc[mf][nf][3]+bv);
        *(ushort4*)(outb + ((size_t)bf*512 + col)*1024 + hw0) = h;
      } else { // MODE 4
        #pragma unroll
        for(int r=0;r<4;++r){
          int m = mb + r;
          if(m < M){
            int cb = (m >= 77) ? 1 : 0;
            int key = m - 77*cb;
            outb[((size_t)cb*512 + col)*128 + key] = f2bf(acc[mf][nf][r] + bv);
          }
        }
      }
    }
  }
}

// ---------------- spatial flash attention v4: S^T + direct-register PV (16x16x16), 64 q/wave
// grid 1D 512: id = qt*128 + head*16 + bz  (qt in high bits -> same (head,bz) share XCD via %8)
__global__ __launch_bounds__(256) void attn_sp_kernel(const unsigned short* __restrict__ Q,
    const unsigned short* __restrict__ K, const unsigned short* __restrict__ VT,
    unsigned short* __restrict__ O){
  int id = blockIdx.x;
  int hb = id & 127, qt = id >> 7;
  int head = hb >> 4, bz = hb & 15;
  int b = bz >> 3, idx = bz & 7;
  int tid = threadIdx.x, wid = tid>>6, l = tid&63, quad = l>>4, ln16 = l&15;
  __shared__ unsigned short vt[64*72];       // [dim][key]
  __shared__ unsigned short kt[64*72];       // [key][dim]
  size_t qbase = (size_t)bz*1024 + qt*256 + wid*64 + ln16;
  short8 qb[4][2];
  #pragma unroll
  for(int grp=0;grp<4;++grp){
    const unsigned short* qp = Q + (qbase + grp*16)*512 + head*64 + quad*8;
    qb[grp][0] = *(const short8*)(qp);
    qb[grp][1] = *(const short8*)(qp + 32);
  }
  floatx4 o[4][4];
  #pragma unroll
  for(int g=0;g<4;++g)
    #pragma unroll
    for(int d=0;d<4;++d) o[g][d] = (floatx4){0,0,0,0};
  float lr[4] = {0.f,0.f,0.f,0.f};
  int nch = idx ? 32 : 16;
  int f0  = idx ? (idx-1) : 0;
  int sr = tid>>2, sc0 = (tid&3)*16;
  short8 pv0, pv1, pk0, pk1;
  {
    const unsigned short* vp = VT + (((size_t)(b*8+f0)*512) + head*64 + sr)*1024 + sc0;
    pv0 = *(const short8*)(vp); pv1 = *(const short8*)(vp + 8);
    const unsigned short* kp = K + (((size_t)(b*8+f0))*1024 + sr)*512 + head*64 + sc0;
    pk0 = *(const short8*)(kp); pk1 = *(const short8*)(kp + 8);
  }
  for(int ch=0; ch<nch; ++ch){
    __syncthreads();
    *(short8*)(vt + sr*72 + sc0)     = pv0;
    *(short8*)(vt + sr*72 + sc0 + 8) = pv1;
    *(short8*)(kt + sr*72 + sc0)     = pk0;
    *(short8*)(kt + sr*72 + sc0 + 8) = pk1;
    if(ch+1 < nch){
      int f = f0 + ((ch+1)>>4);
      int kk0 = ((ch+1)&15)*64;
      const unsigned short* vp = VT + (((size_t)(b*8+f)*512) + head*64 + sr)*1024 + kk0 + sc0;
      pv0 = *(const short8*)(vp); pv1 = *(const short8*)(vp + 8);
      const unsigned short* kp = K + (((size_t)(b*8+f))*1024 + kk0 + sr)*512 + head*64 + sc0;
      pk0 = *(const short8*)(kp); pk1 = *(const short8*)(kp + 8);
    }
    __syncthreads();
    #pragma unroll
    for(int g=0; g<4; ++g){
      const unsigned short* kr = kt + (g*16+ln16)*72 + quad*8;
      short8 k0 = *(const short8*)(kr);
      short8 k1 = *(const short8*)(kr + 32);
      short4v va[4];
      #pragma unroll
      for(int dc=0; dc<4; ++dc)
        va[dc] = *(const short4v*)(vt + (dc*16+ln16)*72 + g*16 + quad*4);
      #pragma unroll
      for(int grp=0; grp<4; ++grp){
        floatx4 s = {0,0,0,0};
        s = MFMA_BF16(k0, qb[grp][0], s, 0,0,0);
        s = MFMA_BF16(k1, qb[grp][1], s, 0,0,0);
        float p0 = __builtin_amdgcn_exp2f(s[0]);
        float p1 = __builtin_amdgcn_exp2f(s[1]);
        float p2 = __builtin_amdgcn_exp2f(s[2]);
        float p3 = __builtin_amdgcn_exp2f(s[3]);
        lr[grp] += (p0+p1)+(p2+p3);
        uint2 pu; pu.x = pack_bf(p0,p1); pu.y = pack_bf(p2,p3);
        short4v pb = __builtin_bit_cast(short4v, pu);
        #pragma unroll
        for(int dc=0; dc<4; ++dc)
          o[grp][dc] = MFMA16(va[dc], pb, o[grp][dc]);
      }
    }
  }
  #pragma unroll
  for(int grp=0; grp<4; ++grp){
    float lt = lr[grp];
    lt += __shfl_xor(lt, 16); lt += __shfl_xor(lt, 32);
    float inv = __builtin_amdgcn_rcpf(lt);
    size_t orow = qbase + grp*16;
    unsigned short* op = O + orow*512 + head*64 + quad*4;
    #pragma unroll
    for(int dc=0; dc<4; ++dc){
      uint2 pk;
      pk.x = pack_bf(o[grp][dc][0]*inv, o[grp][dc][1]*inv);
      pk.y = pack_bf(o[grp][dc][2]*inv, o[grp][dc][3]*inv);
      *(uint2*)(op + dc*16) = pk;
    }
  }
}

// ---------------- cross attention v4: 77 keys (2 chunks of 64, masked), 64 q/wave
__global__ __launch_bounds__(256) void attn_ca_kernel(const unsigned short* __restrict__ Q,
    const unsigned short* __restrict__ K2, const unsigned short* __restrict__ V2T,
    unsigned short* __restrict__ O){
  int id = blockIdx.x;
  int hb = id & 127, qt = id >> 7;
  int head = hb >> 4, bt = hb & 15;
  int cb = bt & 1;
  int tid = threadIdx.x, wid = tid>>6, l = tid&63, quad = l>>4, ln16 = l&15;
  __shared__ unsigned short vt[64*72];
  __shared__ unsigned short kt[64*72];
  size_t qbase = (size_t)bt*1024 + qt*256 + wid*64 + ln16;
  short8 qb[4][2];
  #pragma unroll
  for(int grp=0;grp<4;++grp){
    const unsigned short* qp = Q + (qbase + grp*16)*512 + head*64 + quad*8;
    qb[grp][0] = *(const short8*)(qp);
    qb[grp][1] = *(const short8*)(qp + 32);
  }
  floatx4 o[4][4];
  #pragma unroll
  for(int g=0;g<4;++g)
    #pragma unroll
    for(int d=0;d<4;++d) o[g][d] = (floatx4){0,0,0,0};
  float lr[4] = {0.f,0.f,0.f,0.f};
  int sr = tid>>2, sc0 = (tid&3)*16;
  for(int ch=0; ch<2; ++ch){
    int kk0 = ch*64;
    __syncthreads();
    { const unsigned short* vp = V2T + (((size_t)cb*512) + head*64 + sr)*128 + kk0 + sc0;
      *(short8*)(vt + sr*72 + sc0)     = *(const short8*)(vp);
      *(short8*)(vt + sr*72 + sc0 + 8) = *(const short8*)(vp + 8);
      const unsigned short* kp = K2 + ((size_t)cb*77 + kk0 + sr)*512 + head*64 + sc0;
      *(short8*)(kt + sr*72 + sc0)     = *(const short8*)(kp);
      *(short8*)(kt + sr*72 + sc0 + 8) = *(const short8*)(kp + 8); }
    __syncthreads();
    #pragma unroll
    for(int g=0; g<4; ++g){
      int kg = kk0 + g*16 + quad*4;
      const unsigned short* kr = kt + (g*16+ln16)*72 + quad*8;
      short8 k0 = *(const short8*)(kr);
      short8 k1 = *(const short8*)(kr + 32);
      short4v va[4];
      #pragma unroll
      for(int dc=0; dc<4; ++dc)
        va[dc] = *(const short4v*)(vt + (dc*16+ln16)*72 + g*16 + quad*4);
      #pragma unroll
      for(int grp=0; grp<4; ++grp){
        floatx4 s = {0,0,0,0};
        s = MFMA_BF16(k0, qb[grp][0], s, 0,0,0);
        s = MFMA_BF16(k1, qb[grp][1], s, 0,0,0);
        float p0 = (kg+0 < 77) ? __builtin_amdgcn_exp2f(s[0]) : 0.f;
        float p1 = (kg+1 < 77) ? __builtin_amdgcn_exp2f(s[1]) : 0.f;
        float p2 = (kg+2 < 77) ? __builtin_amdgcn_exp2f(s[2]) : 0.f;
        float p3 = (kg+3 < 77) ? __builtin_amdgcn_exp2f(s[3]) : 0.f;
        lr[grp] += (p0+p1)+(p2+p3);
        uint2 pu; pu.x = pack_bf(p0,p1); pu.y = pack_bf(p2,p3);
        short4v pb = __builtin_bit_cast(short4v, pu);
        #pragma unroll
        for(int dc=0; dc<4; ++dc)
          o[grp][dc] = MFMA16(va[dc], pb, o[grp][dc]);
      }
    }
  }
  #pragma unroll
  for(int grp=0; grp<4; ++grp){
    float lt = lr[grp];
    lt += __shfl_xor(lt, 16); lt += __shfl_xor(lt, 32);
    float inv = __builtin_amdgcn_rcpf(lt);
    size_t orow = qbase + grp*16;
    unsigned short* op = O + orow*512 + head*64 + quad*4;
    #pragma unroll
    for(int dc=0; dc<4; ++dc){
      uint2 pk;
      pk.x = pack_bf(o[grp][dc][0]*inv, o[grp][dc][1]*inv);
      pk.y = pack_bf(o[grp][dc][2]*inv, o[grp][dc][3]*inv);
      *(uint2*)(op + dc*16) = pk;
    }
  }
}

extern "C" void kernel_launch(void* const* d_in, const int* in_sizes, int n_in,
                              void* d_out, int out_size, void* d_ws, size_t ws_size,
                              hipStream_t stream) {
  const float* x        = (const float*)d_in[0];
  const float* ctx      = (const float*)d_in[1];
  const float* gn1w     = (const float*)d_in[2];
  const float* gn1b     = (const float*)d_in[3];
  const float* gn2w     = (const float*)d_in[4];
  const float* gn2b     = (const float*)d_in[5];
  const float* sa_lnv_w = (const float*)d_in[6];
  const float* sa_lnv_b = (const float*)d_in[7];
  const float* sa_lnl_w = (const float*)d_in[8];
  const float* sa_lnl_b = (const float*)d_in[9];
  const float* sa_qw    = (const float*)d_in[10];
  const float* sa_qb    = (const float*)d_in[11];
  const float* sa_kw    = (const float*)d_in[12];
  const float* sa_kb    = (const float*)d_in[13];
  const float* sa_vw    = (const float*)d_in[14];
  const float* sa_vb    = (const float*)d_in[15];
  const float* sa_ow    = (const float*)d_in[16];
  const float* sa_ob    = (const float*)d_in[17];
  const float* sa_gamma = (const float*)d_in[18];
  const float* ca_lnv_w = (const float*)d_in[19];
  const float* ca_lnv_b = (const float*)d_in[20];
  const float* ca_lnl_w = (const float*)d_in[21];
  const float* ca_lnl_b = (const float*)d_in[22];
  const float* ca_qw    = (const float*)d_in[23];
  const float* ca_qb    = (const float*)d_in[24];
  const float* ca_kw    = (const float*)d_in[25];
  const float* ca_kb    = (const float*)d_in[26];
  const float* ca_vw    = (const float*)d_in[27];
  const float* ca_vb    = (const float*)d_in[28];
  const float* ca_ow    = (const float*)d_in[29];
  const float* ca_ob    = (const float*)d_in[30];
  const float* ca_gamma = (const float*)d_in[31];

  const size_t BIGF = (size_t)16384*512*4;   // 33.55 MB
  const size_t BIGH = (size_t)16384*512*2;   // 16.78 MB
  char* w8 = (char*)d_ws;
  float*          xs   = (float*)(w8);
  float*          vn   = (float*)(w8 + BIGF);                  // later reused as vn2
  unsigned short* vnb  = (unsigned short*)(w8 + 2*BIGF);       // later vn2b
  unsigned short* lnlb = (unsigned short*)(w8 + 2*BIGF + 1*BIGH);
  unsigned short* Qb   = (unsigned short*)(w8 + 2*BIGF + 2*BIGH);  // later Q2
  unsigned short* Kb   = (unsigned short*)(w8 + 2*BIGF + 3*BIGH);
  unsigned short* VTb  = (unsigned short*)(w8 + 2*BIGF + 4*BIGH);  // V transposed [(bf)*512+c][1024]
  unsigned short* Ob   = (unsigned short*)(w8 + 2*BIGF + 5*BIGH);
  char* small = w8 + 2*BIGF + 6*BIGH;
  float*          st   = (float*)(small);                 // 4 KB
  unsigned short* ctxb = (unsigned short*)(small + 4096); // 154*512*2
  unsigned short* Wb   = (unsigned short*)(small + 4096 + 157696); // 8 x 512x512 bf16
  // K2b / V2T alias the xs buffer (xs is dead after the sa O-projection)
  unsigned short* K2b  = (unsigned short*)(w8);                     // rows 0..153 valid; reads to 204 finite
  unsigned short* V2T  = (unsigned short*)(w8 + 1048576);           // 2*512*128 bf16
  float* xs2 = (float*)d_out;   // d_out doubles as xs2; fully overwritten by final GEMM

  const float QS = 0.125f * LOG2E;   // fold softmax log2e into Q scale (exp2 path)

  cvtw_kernel<<<dim3(256,8),256,0,stream>>>(sa_qw, sa_kw, sa_vw, sa_ow, ca_qw, ca_kw, ca_vw, ca_ow, Wb);
  gn1_kernel<<<dim3(32,16),256,0,stream>>>(x, gn1w, gn1b, xs);
  ln_dual_kernel<<<4096,256,0,stream>>>(xs, sa_lnv_w, sa_lnv_b, sa_lnl_w, sa_lnl_b, vn, vnb, lnlb);
  gemm64_kernel<0><<<dim3(256,2),256,0,stream>>>(vnb,  Wb+0*262144, sa_qb, 16384, QS,   Qb, nullptr, nullptr, nullptr, nullptr);
  gemm64_kernel<0><<<dim3(256,2),256,0,stream>>>(lnlb, Wb+1*262144, sa_kb, 16384, 1.0f, Kb, nullptr, nullptr, nullptr, nullptr);
  gemm64_kernel<3><<<dim3(256,2),256,0,stream>>>(lnlb, Wb+2*262144, sa_vb, 16384, 1.0f, VTb, nullptr, nullptr, nullptr, nullptr);
  attn_sp_kernel<<<512,256,0,stream>>>(Qb, Kb, VTb, Ob);
  gemm64_kernel<1><<<dim3(256,2),256,0,stream>>>(Ob, Wb+3*262144, sa_ob, 16384, 1.0f, nullptr, xs2, xs, vn, sa_gamma);
  gn2_stats_kernel<<<dim3(32,16),256,0,stream>>>(xs2, st);
  gn2ln_kernel<<<4096,256,0,stream>>>(xs2, st, gn2w, gn2b, ca_lnv_w, ca_lnv_b, vn, vnb);
  ctxln_kernel<<<39,256,0,stream>>>(ctx, ca_lnl_w, ca_lnl_b, ctxb);
  gemm64_kernel<0><<<dim3(3,2),256,0,stream>>>(ctxb, Wb+5*262144, ca_kb, 154, 1.0f, K2b, nullptr, nullptr, nullptr, nullptr);
  (void)hipMemsetAsync(V2T, 0, (size_t)2*512*128*2, stream);
  gemm64_kernel<4><<<dim3(3,2),256,0,stream>>>(ctxb, Wb+6*262144, ca_vb, 154, 1.0f, V2T, nullptr, nullptr, nullptr, nullptr);
  gemm64_kernel<0><<<dim3(256,2),256,0,stream>>>(vnb, Wb+4*262144, ca_qb, 16384, QS, Qb, nullptr, nullptr, nullptr, nullptr);
  attn_ca_kernel<<<512,256,0,stream>>>(Qb, K2b, V2T, Ob);
  gemm64_kernel<2><<<dim3(256,2),256,0,stream>>>(Ob, Wb+7*262144, ca_ob, 16384, 1.0f, nullptr, (float*)d_out, vn, nullptr, ca_gamma);
}

// Round 6
// 577.455 us; speedup vs baseline: 1.9896x; 1.0132x over previous
//
#include <hip/hip_runtime.h>

typedef __attribute__((ext_vector_type(8))) short short8;
typedef __attribute__((ext_vector_type(4))) short short4v;
typedef __attribute__((ext_vector_type(4))) float floatx4;

#define MFMA_BF16 __builtin_amdgcn_mfma_f32_16x16x32_bf16
#define LOG2E 1.44269504088896340736f

// K=16 bf16 MFMA (v_mfma_f32_16x16x16_bf16, A/B = 4 bf16 per lane).
// Guarded so the HIP host pass never parses the target builtin.
__device__ inline floatx4 MFMA16(short4v a, short4v b, floatx4 c){
#if defined(__HIP_DEVICE_COMPILE__)
  return __builtin_amdgcn_mfma_f32_16x16x16bf16_1k(a, b, c, 0, 0, 0);
#else
  return c;
#endif
}

__device__ inline unsigned short f2bf(float x){
  unsigned int u = __float_as_uint(x);
  u += 0x7fffu + ((u >> 16) & 1u);
  return (unsigned short)(u >> 16);
}
// truncating bf16 pair pack: (hi<<16)|lo, 1 instr
__device__ inline unsigned pack_bf(float lo, float hi){
  return __builtin_amdgcn_perm(__float_as_uint(hi), __float_as_uint(lo), 0x07060302u);
}

__device__ inline float wave_sum(float v){
  #pragma unroll
  for(int m=32;m>=1;m>>=1) v += __shfl_xor(v,m);
  return v;
}

// ---------------- GroupNorm1 (stats+apply+transpose). x:(BT,C,HW) -> xs:(BT,HW,C)
__global__ __launch_bounds__(256) void gn1_kernel(const float* __restrict__ x,
    const float* __restrict__ w, const float* __restrict__ b, float* __restrict__ xs){
  int g = blockIdx.x, bt = blockIdx.y, tid = threadIdx.x;
  const float* xp = x + ((size_t)bt*512 + g*16)*1024;
  float s=0.f, s2=0.f;
  #pragma unroll
  for(int it=0; it<16; ++it){
    float4 v = *(const float4*)(xp + it*1024 + tid*4);
    s  += v.x+v.y+v.z+v.w;
    s2 += v.x*v.x+v.y*v.y+v.z*v.z+v.w*v.w;
  }
  __shared__ float red[8];
  s = wave_sum(s); s2 = wave_sum(s2);
  int wid = tid>>6;
  if((tid&63)==0){ red[wid*2]=s; red[wid*2+1]=s2; }
  __syncthreads();
  s  = red[0]+red[2]+red[4]+red[6];
  s2 = red[1]+red[3]+red[5]+red[7];
  float mean = s * (1.f/16384.f);
  float var  = s2 * (1.f/16384.f) - mean*mean;
  float rinv = rsqrtf(var + 1e-5f);
  int c = tid & 15, h0 = tid >> 4;
  float sc = w[g*16+c]*rinv;
  float sh = b[g*16+c] - mean*sc;
  const float* xcol = xp + (size_t)c*1024;
  float* op = xs + (size_t)bt*1024*512 + g*16 + c;
  #pragma unroll 4
  for(int it=0; it<64; ++it){
    int hw = h0 + it*16;
    op[(size_t)hw*512] = xcol[hw]*sc + sh;
  }
}

// ---------------- Dual LayerNorm per row: vn (f32+bf16) with lnv params, lnl (bf16)
__global__ __launch_bounds__(256) void ln_dual_kernel(const float* __restrict__ xs,
    const float* __restrict__ lvw, const float* __restrict__ lvb,
    const float* __restrict__ llw, const float* __restrict__ llb,
    float* __restrict__ vn, unsigned short* __restrict__ vnb, unsigned short* __restrict__ lnlb){
  int wid = threadIdx.x>>6, l = threadIdx.x&63;
  size_t row = (size_t)blockIdx.x*4 + wid;
  const float* xp = xs + row*512;
  float4 a = *(const float4*)(xp + l*4);
  float4 c = *(const float4*)(xp + 256 + l*4);
  float s  = a.x+a.y+a.z+a.w + c.x+c.y+c.z+c.w;
  float s2 = a.x*a.x+a.y*a.y+a.z*a.z+a.w*a.w + c.x*c.x+c.y*c.y+c.z*c.z+c.w*c.w;
  s = wave_sum(s); s2 = wave_sum(s2);
  float mean = s*(1.f/512.f);
  float rinv = rsqrtf(s2*(1.f/512.f) - mean*mean + 1e-5f);
  int c0 = l*4, c1 = 256 + l*4;
  float y[8] = {(a.x-mean)*rinv,(a.y-mean)*rinv,(a.z-mean)*rinv,(a.w-mean)*rinv,
                (c.x-mean)*rinv,(c.y-mean)*rinv,(c.z-mean)*rinv,(c.w-mean)*rinv};
  float4 o0, o1;
  o0.x=y[0]*lvw[c0+0]+lvb[c0+0]; o0.y=y[1]*lvw[c0+1]+lvb[c0+1];
  o0.z=y[2]*lvw[c0+2]+lvb[c0+2]; o0.w=y[3]*lvw[c0+3]+lvb[c0+3];
  o1.x=y[4]*lvw[c1+0]+lvb[c1+0]; o1.y=y[5]*lvw[c1+1]+lvb[c1+1];
  o1.z=y[6]*lvw[c1+2]+lvb[c1+2]; o1.w=y[7]*lvw[c1+3]+lvb[c1+3];
  *(float4*)(vn + row*512 + c0) = o0;
  *(float4*)(vn + row*512 + c1) = o1;
  ushort4 h;
  h.x=f2bf(o0.x); h.y=f2bf(o0.y); h.z=f2bf(o0.z); h.w=f2bf(o0.w);
  *(ushort4*)(vnb + row*512 + c0) = h;
  h.x=f2bf(o1.x); h.y=f2bf(o1.y); h.z=f2bf(o1.z); h.w=f2bf(o1.w);
  *(ushort4*)(vnb + row*512 + c1) = h;
  h.x=f2bf(y[0]*llw[c0+0]+llb[c0+0]); h.y=f2bf(y[1]*llw[c0+1]+llb[c0+1]);
  h.z=f2bf(y[2]*llw[c0+2]+llb[c0+2]); h.w=f2bf(y[3]*llw[c0+3]+llb[c0+3]);
  *(ushort4*)(lnlb + row*512 + c0) = h;
  h.x=f2bf(y[4]*llw[c1+0]+llb[c1+0]); h.y=f2bf(y[5]*llw[c1+1]+llb[c1+1]);
  h.z=f2bf(y[6]*llw[c1+2]+llb[c1+2]); h.w=f2bf(y[7]*llw[c1+3]+llb[c1+3]);
  *(ushort4*)(lnlb + row*512 + c1) = h;
}

// ---------------- GN2 stats on token-major xs2:(BT,HW,C)
__global__ __launch_bounds__(256) void gn2_stats_kernel(const float* __restrict__ xs2, float* __restrict__ st){
  int g = blockIdx.x, bt = blockIdx.y, tid = threadIdx.x;
  const float* xp = xs2 + (size_t)bt*1024*512;
  int c4 = (tid&3)*4, h0 = tid>>2;
  float s=0.f, s2=0.f;
  #pragma unroll
  for(int it=0; it<16; ++it){
    int hw = h0 + it*64;
    float4 v = *(const float4*)(xp + (size_t)hw*512 + g*16 + c4);
    s  += v.x+v.y+v.z+v.w;
    s2 += v.x*v.x+v.y*v.y+v.z*v.z+v.w*v.w;
  }
  __shared__ float red[8];
  s = wave_sum(s); s2 = wave_sum(s2);
  int wid = tid>>6;
  if((tid&63)==0){ red[wid*2]=s; red[wid*2+1]=s2; }
  __syncthreads();
  if(tid==0){
    s  = red[0]+red[2]+red[4]+red[6];
    s2 = red[1]+red[3]+red[5]+red[7];
    float mean = s * (1.f/16384.f);
    float var  = s2 * (1.f/16384.f) - mean*mean;
    st[(bt*32+g)*2]   = mean;
    st[(bt*32+g)*2+1] = rsqrtf(var + 1e-5f);
  }
}

// ---------------- fused GN2-apply + LayerNorm (ca_lnv) -> vn2 f32 + bf16
__global__ __launch_bounds__(256) void gn2ln_kernel(const float* __restrict__ xs2, const float* __restrict__ st,
    const float* __restrict__ gw, const float* __restrict__ gb,
    const float* __restrict__ lw, const float* __restrict__ lb,
    float* __restrict__ vn2, unsigned short* __restrict__ vn2b){
  int wid = threadIdx.x>>6, l = threadIdx.x&63;
  size_t row = (size_t)blockIdx.x*4 + wid;
  int bt = (int)(row >> 10);
  const float* xp = xs2 + row*512;
  float4 a = *(const float4*)(xp + l*4);
  float4 c = *(const float4*)(xp + 256 + l*4);
  int c0 = l*4, c1 = 256 + l*4;
  int g0 = c0>>4, g1 = c1>>4;
  float m0 = st[(bt*32+g0)*2], r0 = st[(bt*32+g0)*2+1];
  float m1 = st[(bt*32+g1)*2], r1 = st[(bt*32+g1)*2+1];
  float y[8];
  y[0]=(a.x-m0)*r0*gw[c0+0]+gb[c0+0]; y[1]=(a.y-m0)*r0*gw[c0+1]+gb[c0+1];
  y[2]=(a.z-m0)*r0*gw[c0+2]+gb[c0+2]; y[3]=(a.w-m0)*r0*gw[c0+3]+gb[c0+3];
  y[4]=(c.x-m1)*r1*gw[c1+0]+gb[c1+0]; y[5]=(c.y-m1)*r1*gw[c1+1]+gb[c1+1];
  y[6]=(c.z-m1)*r1*gw[c1+2]+gb[c1+2]; y[7]=(c.w-m1)*r1*gw[c1+3]+gb[c1+3];
  float s=0.f, s2=0.f;
  #pragma unroll
  for(int i=0;i<8;++i){ s += y[i]; s2 += y[i]*y[i]; }
  s = wave_sum(s); s2 = wave_sum(s2);
  float mean = s*(1.f/512.f);
  float rinv = rsqrtf(s2*(1.f/512.f) - mean*mean + 1e-5f);
  float4 o0, o1;
  o0.x=(y[0]-mean)*rinv*lw[c0+0]+lb[c0+0]; o0.y=(y[1]-mean)*rinv*lw[c0+1]+lb[c0+1];
  o0.z=(y[2]-mean)*rinv*lw[c0+2]+lb[c0+2]; o0.w=(y[3]-mean)*rinv*lw[c0+3]+lb[c0+3];
  o1.x=(y[4]-mean)*rinv*lw[c1+0]+lb[c1+0]; o1.y=(y[5]-mean)*rinv*lw[c1+1]+lb[c1+1];
  o1.z=(y[6]-mean)*rinv*lw[c1+2]+lb[c1+2]; o1.w=(y[7]-mean)*rinv*lw[c1+3]+lb[c1+3];
  *(float4*)(vn2 + row*512 + c0) = o0;
  *(float4*)(vn2 + row*512 + c1) = o1;
  ushort4 h;
  h.x=f2bf(o0.x); h.y=f2bf(o0.y); h.z=f2bf(o0.z); h.w=f2bf(o0.w);
  *(ushort4*)(vn2b + row*512 + c0) = h;
  h.x=f2bf(o1.x); h.y=f2bf(o1.y); h.z=f2bf(o1.z); h.w=f2bf(o1.w);
  *(ushort4*)(vn2b + row*512 + c1) = h;
}

// ---------------- context LayerNorm (ca_lnl) -> bf16, 154 rows
__global__ __launch_bounds__(256) void ctxln_kernel(const float* __restrict__ ctx,
    const float* __restrict__ lw, const float* __restrict__ lb, unsigned short* __restrict__ out){
  int wid = threadIdx.x>>6, l = threadIdx.x&63;
  int row = blockIdx.x*4 + wid;
  if(row >= 154) return;
  const float* xp = ctx + (size_t)row*512;
  float4 a = *(const float4*)(xp + l*4);
  float4 c = *(const float4*)(xp + 256 + l*4);
  float s  = a.x+a.y+a.z+a.w + c.x+c.y+c.z+c.w;
  float s2 = a.x*a.x+a.y*a.y+a.z*a.z+a.w*a.w + c.x*c.x+c.y*c.y+c.z*c.z+c.w*c.w;
  s = wave_sum(s); s2 = wave_sum(s2);
  float mean = s*(1.f/512.f);
  float rinv = rsqrtf(s2*(1.f/512.f) - mean*mean + 1e-5f);
  int c0 = l*4, c1 = 256 + l*4;
  ushort4 h;
  h.x=f2bf((a.x-mean)*rinv*lw[c0+0]+lb[c0+0]); h.y=f2bf((a.y-mean)*rinv*lw[c0+1]+lb[c0+1]);
  h.z=f2bf((a.z-mean)*rinv*lw[c0+2]+lb[c0+2]); h.w=f2bf((a.w-mean)*rinv*lw[c0+3]+lb[c0+3]);
  *(ushort4*)(out + (size_t)row*512 + c0) = h;
  h.x=f2bf((c.x-mean)*rinv*lw[c1+0]+lb[c1+0]); h.y=f2bf((c.y-mean)*rinv*lw[c1+1]+lb[c1+1]);
  h.z=f2bf((c.z-mean)*rinv*lw[c1+2]+lb[c1+2]); h.w=f2bf((c.w-mean)*rinv*lw[c1+3]+lb[c1+3]);
  *(ushort4*)(out + (size_t)row*512 + c1) = h;
}

// ---------------- weight fp32 -> bf16 (8 weights of 512x512)
__global__ __launch_bounds__(256) void cvtw_kernel(const float* s0, const float* s1, const float* s2,
    const float* s3, const float* s4, const float* s5, const float* s6, const float* s7,
    unsigned short* __restrict__ dst){
  const float* srcs[8] = {s0,s1,s2,s3,s4,s5,s6,s7};
  int w = blockIdx.y;
  const float* src = srcs[w];
  int i = (blockIdx.x*256 + threadIdx.x)*4;
  float4 v = *(const float4*)(src + i);
  ushort4 h; h.x=f2bf(v.x); h.y=f2bf(v.y); h.z=f2bf(v.z); h.w=f2bf(v.w);
  *(ushort4*)(dst + (size_t)w*262144 + i) = h;
}

// ---------------- bf16 MFMA GEMM: wave tile 64m x 64n. out[M,512] = A[M,512] @ W[512,512]^T
// MODE 0: outb = bf16((acc+bias)*scale)                       [natural]
// MODE 1: outf = r1 + r2 + gamma*(acc+bias)                   [natural f32]
// MODE 2: outf[bt,c,hw] = r1 + gamma*(acc+bias)               [transposed f32]
// MODE 3: outb transposed bf16: VT[(m>>10)*512+col][m&1023]
// MODE 4: outb = V2T[(cb*512+col)*128 + key], cb=m>=77,key=m-77cb (M=154)
template<int MODE>
__global__ __launch_bounds__(256) void gemm64_kernel(const unsigned short* __restrict__ A,
    const unsigned short* __restrict__ W, const float* __restrict__ bias, int M, float scale,
    unsigned short* __restrict__ outb, float* __restrict__ outf,
    const float* __restrict__ r1, const float* __restrict__ r2, const float* __restrict__ gamma){
  int wid = threadIdx.x>>6, l = threadIdx.x&63, quad = l>>4, ln16 = l&15;
  int m0 = blockIdx.x*64;
  int n0 = blockIdx.y*256 + wid*64;
  const unsigned short* Ap[4];
  #pragma unroll
  for(int mf=0;mf<4;++mf){
    int arow = m0 + mf*16 + ln16; if(arow > M-1) arow = M-1;
    Ap[mf] = A + (size_t)arow*512 + quad*8;
  }
  const unsigned short* Wp = W + (size_t)(n0+ln16)*512 + quad*8;
  floatx4 acc[4][4];
  #pragma unroll
  for(int mf=0;mf<4;++mf)
    #pragma unroll
    for(int nf=0;nf<4;++nf) acc[mf][nf] = (floatx4){0,0,0,0};
  #pragma unroll 2
  for(int k=0;k<512;k+=32){
    short8 av[4], wv[4];
    #pragma unroll
    for(int mf=0;mf<4;++mf) av[mf] = *(const short8*)(Ap[mf] + k);
    #pragma unroll
    for(int nf=0;nf<4;++nf) wv[nf] = *(const short8*)(Wp + nf*16*512 + k);
    #pragma unroll
    for(int mf=0;mf<4;++mf)
      #pragma unroll
      for(int nf=0;nf<4;++nf)
        acc[mf][nf] = MFMA_BF16(av[mf], wv[nf], acc[mf][nf], 0,0,0);
  }
  #pragma unroll
  for(int mf=0;mf<4;++mf){
    int mb = m0 + mf*16 + quad*4;
    #pragma unroll
    for(int nf=0;nf<4;++nf){
      int col = n0 + nf*16 + ln16;
      float bv = bias[col];
      if(MODE==0){
        #pragma unroll
        for(int r=0;r<4;++r){
          int m = mb + r;
          if(m < M) outb[(size_t)m*512 + col] = f2bf((acc[mf][nf][r] + bv)*scale);
        }
      } else if(MODE==1){
        float gv = gamma[col];
        #pragma unroll
        for(int r=0;r<4;++r){
          size_t ix = (size_t)(mb+r)*512 + col;
          outf[ix] = r1[ix] + r2[ix] + gv*(acc[mf][nf][r] + bv);
        }
      } else if(MODE==2){
        float gv = gamma[col];
        int bt = mb >> 10;
        int hw0 = mb & 1023;
        float4 ov;
        ov.x = r1[(size_t)(mb+0)*512+col] + gv*(acc[mf][nf][0]+bv);
        ov.y = r1[(size_t)(mb+1)*512+col] + gv*(acc[mf][nf][1]+bv);
        ov.z = r1[(size_t)(mb+2)*512+col] + gv*(acc[mf][nf][2]+bv);
        ov.w = r1[(size_t)(mb+3)*512+col] + gv*(acc[mf][nf][3]+bv);
        *(float4*)(outf + (size_t)bt*524288 + (size_t)col*1024 + hw0) = ov;
      } else if(MODE==3){
        int bf = mb >> 10;
        int hw0 = mb & 1023;
        ushort4 h;
        h.x = f2bf(acc[mf][nf][0]+bv); h.y = f2bf(acc[mf][nf][1]+bv);
        h.z = f2bf(acc[mf][nf][2]+bv); h.w = f2bf(acc[mf][nf][3]+bv);
        *(ushort4*)(outb + ((size_t)bf*512 + col)*1024 + hw0) = h;
      } else { // MODE 4
        #pragma unroll
        for(int r=0;r<4;++r){
          int m = mb + r;
          if(m < M){
            int cb = (m >= 77) ? 1 : 0;
            int key = m - 77*cb;
            outb[((size_t)cb*512 + col)*128 + key] = f2bf(acc[mf][nf][r] + bv);
          }
        }
      }
    }
  }
}

// ---------------- spatial flash attention v5: 32 q/wave, double-buffered K/V LDS, 1 barrier/chunk
// grid 1D 1024: id = qt*128 + head*16 + bz  (qt high bits -> blocks sharing K/V land on same XCD)
__global__ __launch_bounds__(256) void attn_sp_kernel(const unsigned short* __restrict__ Q,
    const unsigned short* __restrict__ K, const unsigned short* __restrict__ VT,
    unsigned short* __restrict__ O){
  int id = blockIdx.x;
  int hb = id & 127, qt = id >> 7;
  int head = hb >> 4, bz = hb & 15;
  int b = bz >> 3, idx = bz & 7;
  int tid = threadIdx.x, wid = tid>>6, l = tid&63, quad = l>>4, ln16 = l&15;
  __shared__ unsigned short vt[2][64*72];     // [buf][dim][key]
  __shared__ unsigned short kt[2][64*72];     // [buf][key][dim]
  size_t qbase = (size_t)bz*1024 + qt*128 + wid*32 + ln16;
  short8 qb[2][2];
  #pragma unroll
  for(int grp=0;grp<2;++grp){
    const unsigned short* qp = Q + (qbase + grp*16)*512 + head*64 + quad*8;
    qb[grp][0] = *(const short8*)(qp);
    qb[grp][1] = *(const short8*)(qp + 32);
  }
  floatx4 o[2][4];
  #pragma unroll
  for(int g=0;g<2;++g)
    #pragma unroll
    for(int d=0;d<4;++d) o[g][d] = (floatx4){0,0,0,0};
  float lr[2] = {0.f,0.f};
  int nch = idx ? 32 : 16;
  int f0  = idx ? (idx-1) : 0;
  int sr = tid>>2, sc0 = (tid&3)*16;
  short8 pv0, pv1, pk0, pk1;
  {
    const unsigned short* vp = VT + (((size_t)(b*8+f0)*512) + head*64 + sr)*1024 + sc0;
    pv0 = *(const short8*)(vp); pv1 = *(const short8*)(vp + 8);
    const unsigned short* kp = K + (((size_t)(b*8+f0))*1024 + sr)*512 + head*64 + sc0;
    pk0 = *(const short8*)(kp); pk1 = *(const short8*)(kp + 8);
  }
  for(int ch=0; ch<nch; ++ch){
    int bf_ = ch & 1;
    *(short8*)(&vt[bf_][0] + sr*72 + sc0)     = pv0;
    *(short8*)(&vt[bf_][0] + sr*72 + sc0 + 8) = pv1;
    *(short8*)(&kt[bf_][0] + sr*72 + sc0)     = pk0;
    *(short8*)(&kt[bf_][0] + sr*72 + sc0 + 8) = pk1;
    if(ch+1 < nch){
      int f = f0 + ((ch+1)>>4);
      int kk0 = ((ch+1)&15)*64;
      const unsigned short* vp = VT + (((size_t)(b*8+f)*512) + head*64 + sr)*1024 + kk0 + sc0;
      pv0 = *(const short8*)(vp); pv1 = *(const short8*)(vp + 8);
      const unsigned short* kp = K + (((size_t)(b*8+f))*1024 + kk0 + sr)*512 + head*64 + sc0;
      pk0 = *(const short8*)(kp); pk1 = *(const short8*)(kp + 8);
    }
    __syncthreads();
    #pragma unroll
    for(int g=0; g<4; ++g){
      const unsigned short* kr = &kt[bf_][0] + (g*16+ln16)*72 + quad*8;
      short8 k0 = *(const short8*)(kr);
      short8 k1 = *(const short8*)(kr + 32);
      short4v va[4];
      #pragma unroll
      for(int dc=0; dc<4; ++dc)
        va[dc] = *(const short4v*)(&vt[bf_][0] + (dc*16+ln16)*72 + g*16 + quad*4);
      #pragma unroll
      for(int grp=0; grp<2; ++grp){
        floatx4 s = {0,0,0,0};
        s = MFMA_BF16(k0, qb[grp][0], s, 0,0,0);
        s = MFMA_BF16(k1, qb[grp][1], s, 0,0,0);
        float p0 = __builtin_amdgcn_exp2f(s[0]);
        float p1 = __builtin_amdgcn_exp2f(s[1]);
        float p2 = __builtin_amdgcn_exp2f(s[2]);
        float p3 = __builtin_amdgcn_exp2f(s[3]);
        lr[grp] += (p0+p1)+(p2+p3);
        uint2 pu; pu.x = pack_bf(p0,p1); pu.y = pack_bf(p2,p3);
        short4v pb = __builtin_bit_cast(short4v, pu);
        #pragma unroll
        for(int dc=0; dc<4; ++dc)
          o[grp][dc] = MFMA16(va[dc], pb, o[grp][dc]);
      }
    }
  }
  #pragma unroll
  for(int grp=0; grp<2; ++grp){
    float lt = lr[grp];
    lt += __shfl_xor(lt, 16); lt += __shfl_xor(lt, 32);
    float inv = __builtin_amdgcn_rcpf(lt);
    size_t orow = qbase + grp*16;
    unsigned short* op = O + orow*512 + head*64 + quad*4;
    #pragma unroll
    for(int dc=0; dc<4; ++dc){
      uint2 pk;
      pk.x = pack_bf(o[grp][dc][0]*inv, o[grp][dc][1]*inv);
      pk.y = pack_bf(o[grp][dc][2]*inv, o[grp][dc][3]*inv);
      *(uint2*)(op + dc*16) = pk;
    }
  }
}

// ---------------- cross attention v5: 77 keys (2 chunks of 64, masked), 32 q/wave, dbuf
__global__ __launch_bounds__(256) void attn_ca_kernel(const unsigned short* __restrict__ Q,
    const unsigned short* __restrict__ K2, const unsigned short* __restrict__ V2T,
    unsigned short* __restrict__ O){
  int id = blockIdx.x;
  int hb = id & 127, qt = id >> 7;
  int head = hb >> 4, bt = hb & 15;
  int cb = bt & 1;
  int tid = threadIdx.x, wid = tid>>6, l = tid&63, quad = l>>4, ln16 = l&15;
  __shared__ unsigned short vt[2][64*72];
  __shared__ unsigned short kt[2][64*72];
  size_t qbase = (size_t)bt*1024 + qt*128 + wid*32 + ln16;
  short8 qb[2][2];
  #pragma unroll
  for(int grp=0;grp<2;++grp){
    const unsigned short* qp = Q + (qbase + grp*16)*512 + head*64 + quad*8;
    qb[grp][0] = *(const short8*)(qp);
    qb[grp][1] = *(const short8*)(qp + 32);
  }
  floatx4 o[2][4];
  #pragma unroll
  for(int g=0;g<2;++g)
    #pragma unroll
    for(int d=0;d<4;++d) o[g][d] = (floatx4){0,0,0,0};
  float lr[2] = {0.f,0.f};
  int sr = tid>>2, sc0 = (tid&3)*16;
  short8 pv0, pv1, pk0, pk1;
  {
    const unsigned short* vp = V2T + (((size_t)cb*512) + head*64 + sr)*128 + sc0;
    pv0 = *(const short8*)(vp); pv1 = *(const short8*)(vp + 8);
    const unsigned short* kp = K2 + ((size_t)cb*77 + sr)*512 + head*64 + sc0;
    pk0 = *(const short8*)(kp); pk1 = *(const short8*)(kp + 8);
  }
  for(int ch=0; ch<2; ++ch){
    int bf_ = ch & 1;
    int kk0 = ch*64;
    *(short8*)(&vt[bf_][0] + sr*72 + sc0)     = pv0;
    *(short8*)(&vt[bf_][0] + sr*72 + sc0 + 8) = pv1;
    *(short8*)(&kt[bf_][0] + sr*72 + sc0)     = pk0;
    *(short8*)(&kt[bf_][0] + sr*72 + sc0 + 8) = pk1;
    if(ch == 0){
      const unsigned short* vp = V2T + (((size_t)cb*512) + head*64 + sr)*128 + 64 + sc0;
      pv0 = *(const short8*)(vp); pv1 = *(const short8*)(vp + 8);
      const unsigned short* kp = K2 + ((size_t)cb*77 + 64 + sr)*512 + head*64 + sc0;
      pk0 = *(const short8*)(kp); pk1 = *(const short8*)(kp + 8);
    }
    __syncthreads();
    #pragma unroll
    for(int g=0; g<4; ++g){
      int kg = kk0 + g*16 + quad*4;
      const unsigned short* kr = &kt[bf_][0] + (g*16+ln16)*72 + quad*8;
      short8 k0 = *(const short8*)(kr);
      short8 k1 = *(const short8*)(kr + 32);
      short4v va[4];
      #pragma unroll
      for(int dc=0; dc<4; ++dc)
        va[dc] = *(const short4v*)(&vt[bf_][0] + (dc*16+ln16)*72 + g*16 + quad*4);
      #pragma unroll
      for(int grp=0; grp<2; ++grp){
        floatx4 s = {0,0,0,0};
        s = MFMA_BF16(k0, qb[grp][0], s, 0,0,0);
        s = MFMA_BF16(k1, qb[grp][1], s, 0,0,0);
        float p0 = (kg+0 < 77) ? __builtin_amdgcn_exp2f(s[0]) : 0.f;
        float p1 = (kg+1 < 77) ? __builtin_amdgcn_exp2f(s[1]) : 0.f;
        float p2 = (kg+2 < 77) ? __builtin_amdgcn_exp2f(s[2]) : 0.f;
        float p3 = (kg+3 < 77) ? __builtin_amdgcn_exp2f(s[3]) : 0.f;
        lr[grp] += (p0+p1)+(p2+p3);
        uint2 pu; pu.x = pack_bf(p0,p1); pu.y = pack_bf(p2,p3);
        short4v pb = __builtin_bit_cast(short4v, pu);
        #pragma unroll
        for(int dc=0; dc<4; ++dc)
          o[grp][dc] = MFMA16(va[dc], pb, o[grp][dc]);
      }
    }
  }
  #pragma unroll
  for(int grp=0; grp<2; ++grp){
    float lt = lr[grp];
    lt += __shfl_xor(lt, 16); lt += __shfl_xor(lt, 32);
    float inv = __builtin_amdgcn_rcpf(lt);
    size_t orow = qbase + grp*16;
    unsigned short* op = O + orow*512 + head*64 + quad*4;
    #pragma unroll
    for(int dc=0; dc<4; ++dc){
      uint2 pk;
      pk.x = pack_bf(o[grp][dc][0]*inv, o[grp][dc][1]*inv);
      pk.y = pack_bf(o[grp][dc][2]*inv, o[grp][dc][3]*inv);
      *(uint2*)(op + dc*16) = pk;
    }
  }
}

extern "C" void kernel_launch(void* const* d_in, const int* in_sizes, int n_in,
                              void* d_out, int out_size, void* d_ws, size_t ws_size,
                              hipStream_t stream) {
  const float* x        = (const float*)d_in[0];
  const float* ctx      = (const float*)d_in[1];
  const float* gn1w     = (const float*)d_in[2];
  const float* gn1b     = (const float*)d_in[3];
  const float* gn2w     = (const float*)d_in[4];
  const float* gn2b     = (const float*)d_in[5];
  const float* sa_lnv_w = (const float*)d_in[6];
  const float* sa_lnv_b = (const float*)d_in[7];
  const float* sa_lnl_w = (const float*)d_in[8];
  const float* sa_lnl_b = (const float*)d_in[9];
  const float* sa_qw    = (const float*)d_in[10];
  const float* sa_qb    = (const float*)d_in[11];
  const float* sa_kw    = (const float*)d_in[12];
  const float* sa_kb    = (const float*)d_in[13];
  const float* sa_vw    = (const float*)d_in[14];
  const float* sa_vb    = (const float*)d_in[15];
  const float* sa_ow    = (const float*)d_in[16];
  const float* sa_ob    = (const float*)d_in[17];
  const float* sa_gamma = (const float*)d_in[18];
  const float* ca_lnv_w = (const float*)d_in[19];
  const float* ca_lnv_b = (const float*)d_in[20];
  const float* ca_lnl_w = (const float*)d_in[21];
  const float* ca_lnl_b = (const float*)d_in[22];
  const float* ca_qw    = (const float*)d_in[23];
  const float* ca_qb    = (const float*)d_in[24];
  const float* ca_kw    = (const float*)d_in[25];
  const float* ca_kb    = (const float*)d_in[26];
  const float* ca_vw    = (const float*)d_in[27];
  const float* ca_vb    = (const float*)d_in[28];
  const float* ca_ow    = (const float*)d_in[29];
  const float* ca_ob    = (const float*)d_in[30];
  const float* ca_gamma = (const float*)d_in[31];

  const size_t BIGF = (size_t)16384*512*4;   // 33.55 MB
  const size_t BIGH = (size_t)16384*512*2;   // 16.78 MB
  char* w8 = (char*)d_ws;
  float*          xs   = (float*)(w8);
  float*          vn   = (float*)(w8 + BIGF);                  // later reused as vn2
  unsigned short* vnb  = (unsigned short*)(w8 + 2*BIGF);       // later vn2b
  unsigned short* lnlb = (unsigned short*)(w8 + 2*BIGF + 1*BIGH);
  unsigned short* Qb   = (unsigned short*)(w8 + 2*BIGF + 2*BIGH);  // later Q2
  unsigned short* Kb   = (unsigned short*)(w8 + 2*BIGF + 3*BIGH);
  unsigned short* VTb  = (unsigned short*)(w8 + 2*BIGF + 4*BIGH);  // V transposed [(bf)*512+c][1024]
  unsigned short* Ob   = (unsigned short*)(w8 + 2*BIGF + 5*BIGH);
  char* small = w8 + 2*BIGF + 6*BIGH;
  float*          st   = (float*)(small);                 // 4 KB
  unsigned short* ctxb = (unsigned short*)(small + 4096); // 154*512*2
  unsigned short* Wb   = (unsigned short*)(small + 4096 + 157696); // 8 x 512x512 bf16
  // K2b / V2T alias the xs buffer (xs is dead after the sa O-projection)
  unsigned short* K2b  = (unsigned short*)(w8);                     // rows 0..153 valid; reads to 204 finite
  unsigned short* V2T  = (unsigned short*)(w8 + 1048576);           // 2*512*128 bf16
  float* xs2 = (float*)d_out;   // d_out doubles as xs2; fully overwritten by final GEMM

  const float QS = 0.125f * LOG2E;   // fold softmax log2e into Q scale (exp2 path)

  cvtw_kernel<<<dim3(256,8),256,0,stream>>>(sa_qw, sa_kw, sa_vw, sa_ow, ca_qw, ca_kw, ca_vw, ca_ow, Wb);
  gn1_kernel<<<dim3(32,16),256,0,stream>>>(x, gn1w, gn1b, xs);
  ln_dual_kernel<<<4096,256,0,stream>>>(xs, sa_lnv_w, sa_lnv_b, sa_lnl_w, sa_lnl_b, vn, vnb, lnlb);
  gemm64_kernel<0><<<dim3(256,2),256,0,stream>>>(vnb,  Wb+0*262144, sa_qb, 16384, QS,   Qb, nullptr, nullptr, nullptr, nullptr);
  gemm64_kernel<0><<<dim3(256,2),256,0,stream>>>(lnlb, Wb+1*262144, sa_kb, 16384, 1.0f, Kb, nullptr, nullptr, nullptr, nullptr);
  gemm64_kernel<3><<<dim3(256,2),256,0,stream>>>(lnlb, Wb+2*262144, sa_vb, 16384, 1.0f, VTb, nullptr, nullptr, nullptr, nullptr);
  attn_sp_kernel<<<1024,256,0,stream>>>(Qb, Kb, VTb, Ob);
  gemm64_kernel<1><<<dim3(256,2),256,0,stream>>>(Ob, Wb+3*262144, sa_ob, 16384, 1.0f, nullptr, xs2, xs, vn, sa_gamma);
  gn2_stats_kernel<<<dim3(32,16),256,0,stream>>>(xs2, st);
  gn2ln_kernel<<<4096,256,0,stream>>>(xs2, st, gn2w, gn2b, ca_lnv_w, ca_lnv_b, vn, vnb);
  ctxln_kernel<<<39,256,0,stream>>>(ctx, ca_lnl_w, ca_lnl_b, ctxb);
  gemm64_kernel<0><<<dim3(3,2),256,0,stream>>>(ctxb, Wb+5*262144, ca_kb, 154, 1.0f, K2b, nullptr, nullptr, nullptr, nullptr);
  (void)hipMemsetAsync(V2T, 0, (size_t)2*512*128*2, stream);
  gemm64_kernel<4><<<dim3(3,2),256,0,stream>>>(ctxb, Wb+6*262144, ca_vb, 154, 1.0f, V2T, nullptr, nullptr, nullptr, nullptr);
  gemm64_kernel<0><<<dim3(256,2),256,0,stream>>>(vnb, Wb+4*262144, ca_qb, 16384, QS, Qb, nullptr, nullptr, nullptr, nullptr);
  attn_ca_kernel<<<1024,256,0,stream>>>(Qb, K2b, V2T, Ob);
  gemm64_kernel<2><<<dim3(256,2),256,0,stream>>>(Ob, Wb+7*262144, ca_ob, 16384, 1.0f, nullptr, (float*)d_out, vn, nullptr, ca_gamma);
}